// Round 9
// baseline (262.351 us; speedup 1.0000x reference)
//
#include <hip/hip_runtime.h>

// Causal self-attention fwd: x(4,2048,1024)fp32, W_qkv(1024,3072), W_proj(1024,1024)
// Pipeline (5 launches): [k_prep: W transposes + x->bf16 + RoPE table]
//   [GEMM1 qkv + fused V-transpose] [k_ropek: K-RoPE in-place, 32MB]
//   [flash attn w/ fused Q-RoPE] [GEMM2]
// R6: swapped QK^T + in-register P via cvt_pk_bf16 + permlane swaps (no P LDS).
// R11/R12 lesson: K-RoPE fused into GEMM1 epilogue costs ~21us (occupancy drop)
//   -> K-RoPE is its own 32MB kernel; Q-RoPE fused in attn (in-lane, free).
// R13: attn K/V LDS re-layout 64B rows -> 128B rows + XOR swizzle.
//   Evidence: SQ_LDS_BANK_CONFLICT = 4325376 identical in R0 (with P-LDS) and
//   R8 (without) -> conflicts are the K/V b128 reads at 64B row stride (8-way,
//   banks {0,16}), NOT P. [64][64]-short tiles + slot^(l16&7) = the GEMM's
//   measured-0-conflict pattern; staging pre-swizzles global source granule.

#define BATCH 4
#define SEQ   2048
#define DM    1024
#define NH    16
#define HD    64
#define QKV_W 3072

typedef short bf16x8 __attribute__((ext_vector_type(8)));
typedef float f32x4  __attribute__((ext_vector_type(4)));
typedef unsigned u32x4 __attribute__((ext_vector_type(4)));
typedef unsigned short bf16_t;

#define NLT 0.28782313662425575f    // ln(10000)/32

__device__ __forceinline__ unsigned short f2bf(float f) {
  unsigned u = __float_as_uint(f);
  u += 0x7fffu + ((u >> 16) & 1u);   // round-to-nearest-even
  return (unsigned short)(u >> 16);
}
__device__ __forceinline__ float bf2f(unsigned short s) {
  return __uint_as_float((unsigned)s << 16);
}
// async global->LDS, 16B per lane; LDS dest is wave-uniform base + lane*16
__device__ __forceinline__ void gld16(const void* g, void* l) {
  __builtin_amdgcn_global_load_lds(
      (const __attribute__((address_space(1))) unsigned int*)g,
      (__attribute__((address_space(3))) unsigned int*)l, 16, 0, 0);
}
// packed f32x2 -> bf16x2 (RTNE), lo=a hi=b
__device__ __forceinline__ unsigned cvt_pk_bf16(float a, float b) {
  unsigned r;
  asm("v_cvt_pk_bf16_f32 %0, %1, %2" : "=v"(r) : "v"(a), "v"(b));
  return r;
}
// a.rows{2,3} <-> b.rows{0,1}  (rows = 16-lane groups)
__device__ __forceinline__ void permlane32_swap(unsigned& a, unsigned& b) {
  asm("v_permlane32_swap_b32 %0, %1" : "+v"(a), "+v"(b));
}
// a.rows{1,3} <-> b.rows{0,2}
__device__ __forceinline__ void permlane16_swap(unsigned& a, unsigned& b) {
  asm("v_permlane16_swap_b32 %0, %1" : "+v"(a), "+v"(b));
}

// ---- prep: W transposes (fp32->bf16) + x->bf16 + RoPE cos/sin table --------
// blocks [0,3072): Wqkv transpose; [3072,4096): Wproj; [4096,12288): x cvt;
// [12288,12544): tab[s][i] = (cos, sin)(s * 10000^(-i/32)), accurate sincosf.
__global__ __launch_bounds__(256) void k_prep(const float* __restrict__ W1,
                                              const float* __restrict__ W2,
                                              const float* __restrict__ x,
                                              bf16_t* __restrict__ Wt1,
                                              bf16_t* __restrict__ Wt2,
                                              bf16_t* __restrict__ xb,
                                              float2* __restrict__ tab) {
  __shared__ float tile[32][33];
  const int blk = blockIdx.x, tid = threadIdx.x;
  if (blk < 4096) {
    const float* W;
    bf16_t* Wt;
    int N, bx, by;
    if (blk < 3072) { W = W1; Wt = Wt1; N = QKV_W; bx = blk % 96; by = blk / 96; }
    else            { W = W2; Wt = Wt2; N = DM;    bx = (blk - 3072) & 31; by = (blk - 3072) >> 5; }
    const int tx = tid & 31, ty = tid >> 5;   // (32,8)
    const int n0 = bx * 32, k0 = by * 32;
#pragma unroll
    for (int j = 0; j < 4; ++j)
      tile[ty + j * 8][tx] = W[(size_t)(k0 + ty + j * 8) * N + n0 + tx];
    __syncthreads();
#pragma unroll
    for (int j = 0; j < 4; ++j)
      Wt[(size_t)(n0 + ty + j * 8) * DM + k0 + tx] = f2bf(tile[tx][ty + j * 8]);
  } else if (blk < 12288) {
    const int i = ((blk - 4096) * 256 + tid) * 4;
    float4 v = *(const float4*)(x + i);
    unsigned lo = (unsigned)f2bf(v.x) | ((unsigned)f2bf(v.y) << 16);
    unsigned hi = (unsigned)f2bf(v.z) | ((unsigned)f2bf(v.w) << 16);
    *(uint2*)(xb + i) = make_uint2(lo, hi);
  } else {
    const int idx = (blk - 12288) * 256 + tid;   // 0..65535
    const int s = idx >> 5, i = idx & 31;
    const float inv = __expf((float)i * -NLT);
    float sn, cs;
    sincosf((float)s * inv, &sn, &cs);           // accurate
    tab[idx] = make_float2(cs, sn);
  }
}

// ---------------- K-RoPE in place (K section of qkv), table-driven ----------
// 8192 rows x 1024 K-cols bf16 = 16MB; 128 threads/row, bf16x8 (4 pairs) each.
__global__ __launch_bounds__(256) void k_ropek(bf16_t* __restrict__ qkv,
                                               const float2* __restrict__ tab) {
  const int t = blockIdx.x * 256 + threadIdx.x;   // 0..1048575
  const int row = t >> 7;
  const int c = (t & 127) * 8;         // col within K section
  const int i0 = (c & 63) >> 1;        // first pair index in head
  bf16_t* p = qkv + (size_t)row * QKV_W + DM + c;
  bf16x8 v = *(const bf16x8*)p;
  const float2* tq = tab + (size_t)(row & 2047) * 32 + i0;
  bf16x8 r;
#pragma unroll
  for (int k = 0; k < 4; ++k) {
    const float2 cs = tq[k];
    const float e = bf2f((unsigned short)v[2 * k]);
    const float o = bf2f((unsigned short)v[2 * k + 1]);
    r[2 * k]     = (short)f2bf(e * cs.x - o * cs.y);
    r[2 * k + 1] = (short)f2bf(e * cs.y + o * cs.x);
  }
  *(bf16x8*)p = r;
}

// ---------------- 128x128 bf16 GEMM (2-phase, proven 68us, R6 epilogue) -----
// MODE 0: fp32 C (GEMM2). MODE 1: qkv epilogue — cols<2048 (Q,K) bf16
// row-major; cols>=2048 (V) -> vt[b][h][d][s] packed ushort4.
template<int MODE>
__global__ __launch_bounds__(256) void k_gemm(const bf16_t* __restrict__ A,
                                              const bf16_t* __restrict__ Bt,
                                              void* __restrict__ Cout,
                                              bf16_t* __restrict__ vt,
                                              int M, int N, int K) {
  __shared__ __align__(16) short As[128 * 64];
  __shared__ __align__(16) short Bs[128 * 64];
  const int tid = threadIdx.x;
  const int wave = tid >> 6, lane = tid & 63;
  const int quad = lane >> 4, l16 = lane & 15;
  const int wm = (wave >> 1) * 64, wn = (wave & 1) * 64;
  const int bm = blockIdx.y * 128, bn = blockIdx.x * 128;

  f32x4 acc[4][4];
#pragma unroll
  for (int i = 0; i < 4; ++i)
#pragma unroll
    for (int j = 0; j < 4; ++j) acc[i][j] = f32x4{0.f, 0.f, 0.f, 0.f};

  const int srow = tid >> 3;                       // 0..31
  const int sg   = (tid & 7) ^ (srow & 7);         // swizzled source granule
  const bf16_t* Ap = A  + (size_t)(bm + srow) * K + sg * 8;
  const bf16_t* Bp = Bt + (size_t)(bn + srow) * K + sg * 8;
  short* Ad = As + tid * 8;
  short* Bd = Bs + tid * 8;

  for (int k0 = 0; k0 < K; k0 += 64) {
    __syncthreads();
#pragma unroll
    for (int pp = 0; pp < 4; ++pp) {
      gld16(Ap + (size_t)(pp * 32) * K + k0, Ad + pp * 2048);
      gld16(Bp + (size_t)(pp * 32) * K + k0, Bd + pp * 2048);
    }
    __syncthreads();
#pragma unroll
    for (int ks = 0; ks < 2; ++ks) {
      bf16x8 af[4], bfr[4];
#pragma unroll
      for (int i = 0; i < 4; ++i)
        af[i] = *(const bf16x8*)&As[(wm + i * 16 + l16) * 64 +
                                    (((ks * 4 + quad) ^ (l16 & 7)) << 3)];
#pragma unroll
      for (int j = 0; j < 4; ++j)
        bfr[j] = *(const bf16x8*)&Bs[(wn + j * 16 + l16) * 64 +
                                     (((ks * 4 + quad) ^ (l16 & 7)) << 3)];
#pragma unroll
      for (int i = 0; i < 4; ++i)
#pragma unroll
        for (int j = 0; j < 4; ++j)
          acc[i][j] = __builtin_amdgcn_mfma_f32_16x16x32_bf16(af[i], bfr[j], acc[i][j], 0, 0, 0);
    }
  }
  // C row = quad*4+reg, col = l16 (verified mapping)
#pragma unroll
  for (int i = 0; i < 4; ++i)
#pragma unroll
    for (int j = 0; j < 4; ++j) {
      const int col = bn + wn + j * 16 + l16;
      const int row0 = bm + wm + i * 16 + quad * 4;
      if (MODE == 1 && col >= 2048) {
        const int d = col - 2048;
        const int hh = d >> 6, dd = d & 63;
        const int bb = row0 >> 11, ss = row0 & 2047;
        ushort4 pk;
        pk.x = f2bf(acc[i][j][0]); pk.y = f2bf(acc[i][j][1]);
        pk.z = f2bf(acc[i][j][2]); pk.w = f2bf(acc[i][j][3]);
        *(ushort4*)(vt + ((size_t)((bb * NH + hh) * HD + dd)) * SEQ + ss) = pk;
      } else {
#pragma unroll
        for (int r = 0; r < 4; ++r) {
          if (MODE == 1)
            ((bf16_t*)Cout)[(size_t)(row0 + r) * N + col] = f2bf(acc[i][j][r]);
          else
            ((float*)Cout)[(size_t)(row0 + r) * N + col] = acc[i][j][r];
        }
      }
    }
}

// ---------------- flash attention ----------------
// 512 blocks, XCD-swizzled. Block: 128 Q-rows (4 waves x 32q), Q-tiles (p,15-p)
// => uniform 34 KV-iters. KV dbuf + cross-iter prefetch, 1 barrier/iter.
// Q pre-scaled by 0.125*log2e => p = exp2(s'), shift-free (cancels in norm).
// Q-RoPE fused here via table (GEMM1 writes raw Q): pairs in-lane in bf16x8.
// Swapped QK^T: S^T = mfma(K, Q) so each lane holds P[q=l16][k=jn*16+quad*4+r];
// PV A-frags built in-register via cvt_pk + permlane32/16 swaps — no P LDS.
// R13: K/V tiles are [64][64] shorts (128B rows) + slot^(l16&7) XOR swizzle
// (GEMM's measured-0-conflict pattern); staging pre-swizzles source granule.
#define QSCALE 0.18033688011112042f   // 0.125 * log2(e)
__global__ __launch_bounds__(256, 2) void k_attn(const bf16_t* __restrict__ qkv,
                                                 const bf16_t* __restrict__ vt,
                                                 const float2* __restrict__ tab,
                                                 bf16_t* __restrict__ y) {
  __shared__ __align__(16) short Kb[2][64 * 64];   // [buf][kv-row][k-dim]
  __shared__ __align__(16) short Vb[2][64 * 64];   // [buf][d-row][kv-dim]
  const int tid = threadIdx.x;
  const int lane = tid & 63;
  const int quad = lane >> 4, l16 = lane & 15;
  const int wave = tid >> 6;
  const int xs = l16 & 7;
  const int l = blockIdx.x;
  const int p = (l >> 3) & 7;                    // pair index 0..7
  const int g = ((l >> 6) << 3) | (l & 7);       // (h,b) group, const per XCD slice
  const int h = g & 15, b = g >> 4;
  const size_t bbase = (size_t)b * SEQ * QKV_W;
  // staging: thread t -> LDS row (t>>3) and (t>>3)+32, slot t&7;
  // source granule pre-swizzled: sg = (t&7) ^ ((t>>3)&7)  [(r+32)&7 == r&7]
  const int sr8 = tid >> 3;                      // 0..31
  const int sg  = (tid & 7) ^ (sr8 & 7);
  const bf16_t* kbase = qkv + bbase + (size_t)sr8 * QKV_W + DM + h * HD + sg * 8;
  const bf16_t* vbase = vt + ((size_t)(b * NH + h) * HD + sr8) * SEQ + sg * 8;

#define ISSUE(kv0, buf)                                                   \
  do {                                                                    \
    gld16(kbase + (size_t)(kv0) * QKV_W,        &Kb[buf][tid * 8]);       \
    gld16(kbase + (size_t)((kv0) + 32) * QKV_W, &Kb[buf][2048 + tid * 8]);\
    gld16(vbase + (kv0),                        &Vb[buf][tid * 8]);       \
    gld16(vbase + (size_t)32 * SEQ + (kv0),     &Vb[buf][2048 + tid * 8]);\
  } while (0)

  int bufp = 0;
  ISSUE(0, 0);
  for (int half = 0; half < 2; ++half) {
    const int qt = half ? (15 - p) : p;
    const int qb = qt * 128 + wave * 32;         // wave's first q row
    // load Q fragments; apply RoPE (in-lane pairs, table) + QSCALE in fp32
    bf16x8 aq[2][2];
#pragma unroll
    for (int mi = 0; mi < 2; ++mi) {
      const float2* tq = tab + (size_t)(qb + mi * 16 + l16) * 32;
#pragma unroll
      for (int kk = 0; kk < 2; ++kk) {
        const bf16_t* qp = qkv + bbase + (size_t)(qb + mi * 16 + l16) * QKV_W +
                           h * HD + kk * 32 + quad * 8;
        bf16x8 raw = *(const bf16x8*)qp;
        bf16x8 sc;
#pragma unroll
        for (int t = 0; t < 4; ++t) {
          const float2 cs = tq[kk * 16 + quad * 4 + t];
          const float e = bf2f((unsigned short)raw[2 * t]);
          const float o = bf2f((unsigned short)raw[2 * t + 1]);
          sc[2 * t]     = (short)f2bf((e * cs.x - o * cs.y) * QSCALE);
          sc[2 * t + 1] = (short)f2bf((e * cs.y + o * cs.x) * QSCALE);
        }
        aq[mi][kk] = sc;
      }
    }
    f32x4 o[2][4];
    float lsum[2];
#pragma unroll
    for (int mi = 0; mi < 2; ++mi) {
      lsum[mi] = 0.f;
#pragma unroll
      for (int jn = 0; jn < 4; ++jn) o[mi][jn] = f32x4{0.f, 0.f, 0.f, 0.f};
    }
    const int qr0 = qb + l16;                    // this lane's q row (mi=0)

    const int jmax = 2 * qt + 1;
    for (int j = 0; j <= jmax; ++j) {
      const int kv0 = j * 64;
      __syncthreads();   // drains this buf's loads; WAR-protects prefetch target
      if (j < jmax)          ISSUE(kv0 + 64, bufp ^ 1);
      else if (half == 0)    ISSUE(0, bufp ^ 1);
      if (kv0 <= qb + 31) {  // else: fully masked for this wave — skip
        const bool needmask = (kv0 + 63 > qb);
        const short* Kc = &Kb[bufp][0];
        const short* Vc = &Vb[bufp][0];

        // S^T frags: st[jn][mi]; row = kv (jn*16+quad*4+r), col = q (mi*16+l16)
        f32x4 st[4][2];
#pragma unroll
        for (int jn = 0; jn < 4; ++jn) {
          const int krow = (jn * 16 + l16) * 64;
          bf16x8 ak0 = *(const bf16x8*)&Kc[krow + ((quad ^ xs) << 3)];
          bf16x8 ak1 = *(const bf16x8*)&Kc[krow + (((4 + quad) ^ xs) << 3)];
#pragma unroll
          for (int mi = 0; mi < 2; ++mi) {
            f32x4 s4 = f32x4{0.f, 0.f, 0.f, 0.f};
            s4 = __builtin_amdgcn_mfma_f32_16x16x32_bf16(ak0, aq[mi][0], s4, 0, 0, 0);
            s4 = __builtin_amdgcn_mfma_f32_16x16x32_bf16(ak1, aq[mi][1], s4, 0, 0, 0);
            st[jn][mi] = s4;
          }
        }
        // p = exp2(s'); mask near diagonal; pack r-pairs to bf16x2
        unsigned pk[4][2][2];
#pragma unroll
        for (int jn = 0; jn < 4; ++jn)
#pragma unroll
          for (int mi = 0; mi < 2; ++mi) {
            const int kvb = kv0 + jn * 16 + quad * 4;
            const int qr = qr0 + mi * 16;
            float e[4];
#pragma unroll
            for (int r = 0; r < 4; ++r) {
              float v = __builtin_amdgcn_exp2f(st[jn][mi][r]);
              if (needmask) v = (kvb + r <= qr) ? v : 0.f;
              lsum[mi] += v;
              e[r] = v;
            }
            pk[jn][mi][0] = cvt_pk_bf16(e[0], e[1]);
            pk[jn][mi][1] = cvt_pk_bf16(e[2], e[3]);
          }
        // redistribute across quads -> PV A-frags ap[mi][ks]
        bf16x8 ap[2][2];
#pragma unroll
        for (int mi = 0; mi < 2; ++mi)
#pragma unroll
          for (int ks = 0; ks < 2; ++ks) {
            unsigned a0 = pk[2 * ks][mi][0], b0 = pk[2 * ks + 1][mi][0];
            permlane32_swap(a0, b0);
            permlane16_swap(a0, b0);
            unsigned a1 = pk[2 * ks][mi][1], b1 = pk[2 * ks + 1][mi][1];
            permlane32_swap(a1, b1);
            permlane16_swap(a1, b1);
            union { u32x4 u; bf16x8 s; } f;
            f.u = (u32x4){a0, a1, b0, b1};
            ap[mi][ks] = f.s;
          }
        // O += P V  (V frags shared across mi)
#pragma unroll
        for (int ks = 0; ks < 2; ++ks) {
#pragma unroll
          for (int jn = 0; jn < 4; ++jn) {
            bf16x8 bv = *(const bf16x8*)&Vc[(jn * 16 + l16) * 64 +
                                            (((ks * 4 + quad) ^ xs) << 3)];
            o[0][jn] = __builtin_amdgcn_mfma_f32_16x16x32_bf16(ap[0][ks], bv, o[0][jn], 0, 0, 0);
            o[1][jn] = __builtin_amdgcn_mfma_f32_16x16x32_bf16(ap[1][ks], bv, o[1][jn], 0, 0, 0);
          }
        }
      }
      bufp ^= 1;
    }
    // normalize + write: lane holds full row-sum for q = l16 (+mi*16) after
    // quad-reduce; redistribute inv to output rows (quad*4+r) via shfl.
#pragma unroll
    for (int mi = 0; mi < 2; ++mi) {
      float s = lsum[mi];
      s += __shfl_xor(s, 16, 64);
      s += __shfl_xor(s, 32, 64);
      const float inv = 1.0f / s;
#pragma unroll
      for (int r = 0; r < 4; ++r) {
        const float invr = __shfl(inv, quad * 4 + r, 64);
        const int qr = qb + mi * 16 + quad * 4 + r;
        bf16_t* yp = y + ((size_t)b * SEQ + qr) * DM + h * HD;
#pragma unroll
        for (int jn = 0; jn < 4; ++jn)
          yp[jn * 16 + l16] = f2bf(o[mi][jn][r] * invr);
      }
    }
  }
#undef ISSUE
}

extern "C" void kernel_launch(void* const* d_in, const int* in_sizes, int n_in,
                              void* d_out, int out_size, void* d_ws, size_t ws_size,
                              hipStream_t stream) {
  const float* x     = (const float*)d_in[0];
  const float* Wqkv  = (const float*)d_in[1];
  const float* Wproj = (const float*)d_in[2];
  float* out = (float*)d_out;
  char* ws = (char*)d_ws;
  // ws layout (72 MiB):
  bf16_t* qkv = (bf16_t*)(ws);                 // 48 MiB (V third unused)
  bf16_t* Wt1 = (bf16_t*)(ws + 50331648);      // 6 MiB
  bf16_t* Wt2 = (bf16_t*)(ws + 56623104);      // 2 MiB
  bf16_t* xb  = (bf16_t*)(ws + 58720256);      // 16 MiB (dead after GEMM1)
  bf16_t* y   = xb;                            // attn output aliases xb
  // d_out scratch: V^T in first 16 MiB, RoPE table in next 512 KiB; both dead
  // before GEMM2 overwrites d_out.
  bf16_t* vt  = (bf16_t*)d_out;
  float2* tab = (float2*)((char*)d_out + 16777216);

  k_prep<<<12544, 256, 0, stream>>>(Wqkv, Wproj, x, Wt1, Wt2, xb, tab);
  k_gemm<1><<<dim3(QKV_W / 128, (BATCH * SEQ) / 128), 256, 0, stream>>>(
      xb, Wt1, qkv, vt, BATCH * SEQ, QKV_W, DM);
  k_ropek<<<4096, 256, 0, stream>>>(qkv, tab);
  k_attn<<<512, 256, 0, stream>>>(qkv, vt, tab, y);
  k_gemm<0><<<dim3(DM / 128, (BATCH * SEQ) / 128), 256, 0, stream>>>(
      y, Wt2, out, nullptr, BATCH * SEQ, DM, DM);
}

// Round 10
// 248.604 us; speedup vs baseline: 1.0553x; 1.0553x over previous
//
#include <hip/hip_runtime.h>

// Causal self-attention fwd: x(4,2048,1024)fp32, W_qkv(1024,3072), W_proj(1024,1024)
// Pipeline (5 launches): [k_prep: W transposes + x->bf16 + RoPE table]
//   [GEMM1 qkv + fused V-transpose] [k_ropek: K-RoPE in-place, 32MB]
//   [flash attn w/ fused Q-RoPE] [GEMM2]
// R6: swapped QK^T + in-register P via cvt_pk_bf16 + permlane swaps (no P LDS).
// R11/R12: K-RoPE fused in GEMM1 epilogue costs ~21us -> own 32MB kernel.
// R13: K/V LDS 128B rows + XOR swizzle -> conflicts 4.3M -> 0 (dur unchanged ->
//   attn is latency-bound, not conflict-bound).
// R14: occupancy attack. Old: 512 blocks (paired Q-tiles) = 2 blocks/CU,
//   Occ 18%, MfmaUtil 20%, VALUBusy 47% -> stalled serial chain, no TLP.
//   New: ONE Q-tile per block -> 1024 blocks = 4+/CU (VGPR 68 / LDS 32KB both
//   allow it), longest-tile-first ordering (qt = 15 - blk/64) so the hardware
//   scheduler load-balances; launch_bounds(256,4). Same total work.

#define BATCH 4
#define SEQ   2048
#define DM    1024
#define NH    16
#define HD    64
#define QKV_W 3072

typedef short bf16x8 __attribute__((ext_vector_type(8)));
typedef float f32x4  __attribute__((ext_vector_type(4)));
typedef unsigned u32x4 __attribute__((ext_vector_type(4)));
typedef unsigned short bf16_t;

#define NLT 0.28782313662425575f    // ln(10000)/32

__device__ __forceinline__ unsigned short f2bf(float f) {
  unsigned u = __float_as_uint(f);
  u += 0x7fffu + ((u >> 16) & 1u);   // round-to-nearest-even
  return (unsigned short)(u >> 16);
}
__device__ __forceinline__ float bf2f(unsigned short s) {
  return __uint_as_float((unsigned)s << 16);
}
// async global->LDS, 16B per lane; LDS dest is wave-uniform base + lane*16
__device__ __forceinline__ void gld16(const void* g, void* l) {
  __builtin_amdgcn_global_load_lds(
      (const __attribute__((address_space(1))) unsigned int*)g,
      (__attribute__((address_space(3))) unsigned int*)l, 16, 0, 0);
}
// packed f32x2 -> bf16x2 (RTNE), lo=a hi=b
__device__ __forceinline__ unsigned cvt_pk_bf16(float a, float b) {
  unsigned r;
  asm("v_cvt_pk_bf16_f32 %0, %1, %2" : "=v"(r) : "v"(a), "v"(b));
  return r;
}
// a.rows{2,3} <-> b.rows{0,1}  (rows = 16-lane groups)
__device__ __forceinline__ void permlane32_swap(unsigned& a, unsigned& b) {
  asm("v_permlane32_swap_b32 %0, %1" : "+v"(a), "+v"(b));
}
// a.rows{1,3} <-> b.rows{0,2}
__device__ __forceinline__ void permlane16_swap(unsigned& a, unsigned& b) {
  asm("v_permlane16_swap_b32 %0, %1" : "+v"(a), "+v"(b));
}

// ---- prep: W transposes (fp32->bf16) + x->bf16 + RoPE cos/sin table --------
// blocks [0,3072): Wqkv transpose; [3072,4096): Wproj; [4096,12288): x cvt;
// [12288,12544): tab[s][i] = (cos, sin)(s * 10000^(-i/32)), accurate sincosf.
__global__ __launch_bounds__(256) void k_prep(const float* __restrict__ W1,
                                              const float* __restrict__ W2,
                                              const float* __restrict__ x,
                                              bf16_t* __restrict__ Wt1,
                                              bf16_t* __restrict__ Wt2,
                                              bf16_t* __restrict__ xb,
                                              float2* __restrict__ tab) {
  __shared__ float tile[32][33];
  const int blk = blockIdx.x, tid = threadIdx.x;
  if (blk < 4096) {
    const float* W;
    bf16_t* Wt;
    int N, bx, by;
    if (blk < 3072) { W = W1; Wt = Wt1; N = QKV_W; bx = blk % 96; by = blk / 96; }
    else            { W = W2; Wt = Wt2; N = DM;    bx = (blk - 3072) & 31; by = (blk - 3072) >> 5; }
    const int tx = tid & 31, ty = tid >> 5;   // (32,8)
    const int n0 = bx * 32, k0 = by * 32;
#pragma unroll
    for (int j = 0; j < 4; ++j)
      tile[ty + j * 8][tx] = W[(size_t)(k0 + ty + j * 8) * N + n0 + tx];
    __syncthreads();
#pragma unroll
    for (int j = 0; j < 4; ++j)
      Wt[(size_t)(n0 + ty + j * 8) * DM + k0 + tx] = f2bf(tile[tx][ty + j * 8]);
  } else if (blk < 12288) {
    const int i = ((blk - 4096) * 256 + tid) * 4;
    float4 v = *(const float4*)(x + i);
    unsigned lo = (unsigned)f2bf(v.x) | ((unsigned)f2bf(v.y) << 16);
    unsigned hi = (unsigned)f2bf(v.z) | ((unsigned)f2bf(v.w) << 16);
    *(uint2*)(xb + i) = make_uint2(lo, hi);
  } else {
    const int idx = (blk - 12288) * 256 + tid;   // 0..65535
    const int s = idx >> 5, i = idx & 31;
    const float inv = __expf((float)i * -NLT);
    float sn, cs;
    sincosf((float)s * inv, &sn, &cs);           // accurate
    tab[idx] = make_float2(cs, sn);
  }
}

// ---------------- K-RoPE in place (K section of qkv), table-driven ----------
// 8192 rows x 1024 K-cols bf16 = 16MB; 128 threads/row, bf16x8 (4 pairs) each.
__global__ __launch_bounds__(256) void k_ropek(bf16_t* __restrict__ qkv,
                                               const float2* __restrict__ tab) {
  const int t = blockIdx.x * 256 + threadIdx.x;   // 0..1048575
  const int row = t >> 7;
  const int c = (t & 127) * 8;         // col within K section
  const int i0 = (c & 63) >> 1;        // first pair index in head
  bf16_t* p = qkv + (size_t)row * QKV_W + DM + c;
  bf16x8 v = *(const bf16x8*)p;
  const float2* tq = tab + (size_t)(row & 2047) * 32 + i0;
  bf16x8 r;
#pragma unroll
  for (int k = 0; k < 4; ++k) {
    const float2 cs = tq[k];
    const float e = bf2f((unsigned short)v[2 * k]);
    const float o = bf2f((unsigned short)v[2 * k + 1]);
    r[2 * k]     = (short)f2bf(e * cs.x - o * cs.y);
    r[2 * k + 1] = (short)f2bf(e * cs.y + o * cs.x);
  }
  *(bf16x8*)p = r;
}

// ---------------- 128x128 bf16 GEMM (2-phase, proven 68us, R6 epilogue) -----
// MODE 0: fp32 C (GEMM2). MODE 1: qkv epilogue — cols<2048 (Q,K) bf16
// row-major; cols>=2048 (V) -> vt[b][h][d][s] packed ushort4.
template<int MODE>
__global__ __launch_bounds__(256) void k_gemm(const bf16_t* __restrict__ A,
                                              const bf16_t* __restrict__ Bt,
                                              void* __restrict__ Cout,
                                              bf16_t* __restrict__ vt,
                                              int M, int N, int K) {
  __shared__ __align__(16) short As[128 * 64];
  __shared__ __align__(16) short Bs[128 * 64];
  const int tid = threadIdx.x;
  const int wave = tid >> 6, lane = tid & 63;
  const int quad = lane >> 4, l16 = lane & 15;
  const int wm = (wave >> 1) * 64, wn = (wave & 1) * 64;
  const int bm = blockIdx.y * 128, bn = blockIdx.x * 128;

  f32x4 acc[4][4];
#pragma unroll
  for (int i = 0; i < 4; ++i)
#pragma unroll
    for (int j = 0; j < 4; ++j) acc[i][j] = f32x4{0.f, 0.f, 0.f, 0.f};

  const int srow = tid >> 3;                       // 0..31
  const int sg   = (tid & 7) ^ (srow & 7);         // swizzled source granule
  const bf16_t* Ap = A  + (size_t)(bm + srow) * K + sg * 8;
  const bf16_t* Bp = Bt + (size_t)(bn + srow) * K + sg * 8;
  short* Ad = As + tid * 8;
  short* Bd = Bs + tid * 8;

  for (int k0 = 0; k0 < K; k0 += 64) {
    __syncthreads();
#pragma unroll
    for (int pp = 0; pp < 4; ++pp) {
      gld16(Ap + (size_t)(pp * 32) * K + k0, Ad + pp * 2048);
      gld16(Bp + (size_t)(pp * 32) * K + k0, Bd + pp * 2048);
    }
    __syncthreads();
#pragma unroll
    for (int ks = 0; ks < 2; ++ks) {
      bf16x8 af[4], bfr[4];
#pragma unroll
      for (int i = 0; i < 4; ++i)
        af[i] = *(const bf16x8*)&As[(wm + i * 16 + l16) * 64 +
                                    (((ks * 4 + quad) ^ (l16 & 7)) << 3)];
#pragma unroll
      for (int j = 0; j < 4; ++j)
        bfr[j] = *(const bf16x8*)&Bs[(wn + j * 16 + l16) * 64 +
                                     (((ks * 4 + quad) ^ (l16 & 7)) << 3)];
#pragma unroll
      for (int i = 0; i < 4; ++i)
#pragma unroll
        for (int j = 0; j < 4; ++j)
          acc[i][j] = __builtin_amdgcn_mfma_f32_16x16x32_bf16(af[i], bfr[j], acc[i][j], 0, 0, 0);
    }
  }
  // C row = quad*4+reg, col = l16 (verified mapping)
#pragma unroll
  for (int i = 0; i < 4; ++i)
#pragma unroll
    for (int j = 0; j < 4; ++j) {
      const int col = bn + wn + j * 16 + l16;
      const int row0 = bm + wm + i * 16 + quad * 4;
      if (MODE == 1 && col >= 2048) {
        const int d = col - 2048;
        const int hh = d >> 6, dd = d & 63;
        const int bb = row0 >> 11, ss = row0 & 2047;
        ushort4 pk;
        pk.x = f2bf(acc[i][j][0]); pk.y = f2bf(acc[i][j][1]);
        pk.z = f2bf(acc[i][j][2]); pk.w = f2bf(acc[i][j][3]);
        *(ushort4*)(vt + ((size_t)((bb * NH + hh) * HD + dd)) * SEQ + ss) = pk;
      } else {
#pragma unroll
        for (int r = 0; r < 4; ++r) {
          if (MODE == 1)
            ((bf16_t*)Cout)[(size_t)(row0 + r) * N + col] = f2bf(acc[i][j][r]);
          else
            ((float*)Cout)[(size_t)(row0 + r) * N + col] = acc[i][j][r];
        }
      }
    }
}

// ---------------- flash attention ----------------
// R14: 1024 blocks, ONE 128-row Q-tile each (4 waves x 32q), longest-first
// (qt = 15 - blk/64) for load balance; 4+ blocks/CU. KV dbuf + cross-iter
// prefetch, 1 barrier/iter. Q pre-scaled by 0.125*log2e => p = exp2(s').
// Q-RoPE fused via table; pairs in-lane in bf16x8.
// Swapped QK^T: S^T = mfma(K, Q) so each lane holds P[q=l16][k=jn*16+quad*4+r];
// PV A-frags built in-register via cvt_pk + permlane32/16 swaps — no P LDS.
// K/V tiles [64][64] shorts (128B rows) + slot^(l16&7) XOR swizzle (0-conflict).
#define QSCALE 0.18033688011112042f   // 0.125 * log2(e)
__global__ __launch_bounds__(256, 4) void k_attn(const bf16_t* __restrict__ qkv,
                                                 const bf16_t* __restrict__ vt,
                                                 const float2* __restrict__ tab,
                                                 bf16_t* __restrict__ y) {
  __shared__ __align__(16) short Kb[2][64 * 64];   // [buf][kv-row][k-dim]
  __shared__ __align__(16) short Vb[2][64 * 64];   // [buf][d-row][kv-dim]
  const int tid = threadIdx.x;
  const int lane = tid & 63;
  const int quad = lane >> 4, l16 = lane & 15;
  const int wave = tid >> 6;
  const int xs = l16 & 7;
  const int l = blockIdx.x;
  const int qt = 15 - (l >> 6);                  // longest tiles first
  const int hb = l & 63;
  const int h = hb & 15, b = hb >> 4;
  const size_t bbase = (size_t)b * SEQ * QKV_W;
  // staging: thread t -> LDS row (t>>3) and (t>>3)+32, slot t&7;
  // source granule pre-swizzled: sg = (t&7) ^ ((t>>3)&7)  [(r+32)&7 == r&7]
  const int sr8 = tid >> 3;                      // 0..31
  const int sg  = (tid & 7) ^ (sr8 & 7);
  const bf16_t* kbase = qkv + bbase + (size_t)sr8 * QKV_W + DM + h * HD + sg * 8;
  const bf16_t* vbase = vt + ((size_t)(b * NH + h) * HD + sr8) * SEQ + sg * 8;

#define ISSUE(kv0, buf)                                                   \
  do {                                                                    \
    gld16(kbase + (size_t)(kv0) * QKV_W,        &Kb[buf][tid * 8]);       \
    gld16(kbase + (size_t)((kv0) + 32) * QKV_W, &Kb[buf][2048 + tid * 8]);\
    gld16(vbase + (kv0),                        &Vb[buf][tid * 8]);       \
    gld16(vbase + (size_t)32 * SEQ + (kv0),     &Vb[buf][2048 + tid * 8]);\
  } while (0)

  int bufp = 0;
  ISSUE(0, 0);
  const int qb = qt * 128 + wave * 32;           // wave's first q row
  // load Q fragments; apply RoPE (in-lane pairs, table) + QSCALE in fp32
  bf16x8 aq[2][2];
#pragma unroll
  for (int mi = 0; mi < 2; ++mi) {
    const float2* tq = tab + (size_t)(qb + mi * 16 + l16) * 32;
#pragma unroll
    for (int kk = 0; kk < 2; ++kk) {
      const bf16_t* qp = qkv + bbase + (size_t)(qb + mi * 16 + l16) * QKV_W +
                         h * HD + kk * 32 + quad * 8;
      bf16x8 raw = *(const bf16x8*)qp;
      bf16x8 sc;
#pragma unroll
      for (int t = 0; t < 4; ++t) {
        const float2 cs = tq[kk * 16 + quad * 4 + t];
        const float e = bf2f((unsigned short)raw[2 * t]);
        const float o = bf2f((unsigned short)raw[2 * t + 1]);
        sc[2 * t]     = (short)f2bf((e * cs.x - o * cs.y) * QSCALE);
        sc[2 * t + 1] = (short)f2bf((e * cs.y + o * cs.x) * QSCALE);
      }
      aq[mi][kk] = sc;
    }
  }
  f32x4 o[2][4];
  float lsum[2];
#pragma unroll
  for (int mi = 0; mi < 2; ++mi) {
    lsum[mi] = 0.f;
#pragma unroll
    for (int jn = 0; jn < 4; ++jn) o[mi][jn] = f32x4{0.f, 0.f, 0.f, 0.f};
  }
  const int qr0 = qb + l16;                      // this lane's q row (mi=0)

  const int jmax = 2 * qt + 1;
  for (int j = 0; j <= jmax; ++j) {
    const int kv0 = j * 64;
    __syncthreads();   // drains this buf's loads; WAR-protects prefetch target
    if (j < jmax) ISSUE(kv0 + 64, bufp ^ 1);
    if (kv0 <= qb + 31) {  // else: fully masked for this wave — skip
      const bool needmask = (kv0 + 63 > qb);
      const short* Kc = &Kb[bufp][0];
      const short* Vc = &Vb[bufp][0];

      // S^T frags: st[jn][mi]; row = kv (jn*16+quad*4+r), col = q (mi*16+l16)
      f32x4 st[4][2];
#pragma unroll
      for (int jn = 0; jn < 4; ++jn) {
        const int krow = (jn * 16 + l16) * 64;
        bf16x8 ak0 = *(const bf16x8*)&Kc[krow + ((quad ^ xs) << 3)];
        bf16x8 ak1 = *(const bf16x8*)&Kc[krow + (((4 + quad) ^ xs) << 3)];
#pragma unroll
        for (int mi = 0; mi < 2; ++mi) {
          f32x4 s4 = f32x4{0.f, 0.f, 0.f, 0.f};
          s4 = __builtin_amdgcn_mfma_f32_16x16x32_bf16(ak0, aq[mi][0], s4, 0, 0, 0);
          s4 = __builtin_amdgcn_mfma_f32_16x16x32_bf16(ak1, aq[mi][1], s4, 0, 0, 0);
          st[jn][mi] = s4;
        }
      }
      // p = exp2(s'); mask near diagonal; pack r-pairs to bf16x2
      unsigned pk[4][2][2];
#pragma unroll
      for (int jn = 0; jn < 4; ++jn)
#pragma unroll
        for (int mi = 0; mi < 2; ++mi) {
          const int kvb = kv0 + jn * 16 + quad * 4;
          const int qr = qr0 + mi * 16;
          float e[4];
#pragma unroll
          for (int r = 0; r < 4; ++r) {
            float v = __builtin_amdgcn_exp2f(st[jn][mi][r]);
            if (needmask) v = (kvb + r <= qr) ? v : 0.f;
            lsum[mi] += v;
            e[r] = v;
          }
          pk[jn][mi][0] = cvt_pk_bf16(e[0], e[1]);
          pk[jn][mi][1] = cvt_pk_bf16(e[2], e[3]);
        }
      // redistribute across quads -> PV A-frags ap[mi][ks]
      bf16x8 ap[2][2];
#pragma unroll
      for (int mi = 0; mi < 2; ++mi)
#pragma unroll
        for (int ks = 0; ks < 2; ++ks) {
          unsigned a0 = pk[2 * ks][mi][0], b0 = pk[2 * ks + 1][mi][0];
          permlane32_swap(a0, b0);
          permlane16_swap(a0, b0);
          unsigned a1 = pk[2 * ks][mi][1], b1 = pk[2 * ks + 1][mi][1];
          permlane32_swap(a1, b1);
          permlane16_swap(a1, b1);
          union { u32x4 u; bf16x8 s; } f;
          f.u = (u32x4){a0, a1, b0, b1};
          ap[mi][ks] = f.s;
        }
      // O += P V  (V frags shared across mi)
#pragma unroll
      for (int ks = 0; ks < 2; ++ks) {
#pragma unroll
        for (int jn = 0; jn < 4; ++jn) {
          bf16x8 bv = *(const bf16x8*)&Vc[(jn * 16 + l16) * 64 +
                                          (((ks * 4 + quad) ^ xs) << 3)];
          o[0][jn] = __builtin_amdgcn_mfma_f32_16x16x32_bf16(ap[0][ks], bv, o[0][jn], 0, 0, 0);
          o[1][jn] = __builtin_amdgcn_mfma_f32_16x16x32_bf16(ap[1][ks], bv, o[1][jn], 0, 0, 0);
        }
      }
    }
    bufp ^= 1;
  }
  // normalize + write: lane holds full row-sum for q = l16 (+mi*16) after
  // quad-reduce; redistribute inv to output rows (quad*4+r) via shfl.
#pragma unroll
  for (int mi = 0; mi < 2; ++mi) {
    float s = lsum[mi];
    s += __shfl_xor(s, 16, 64);
    s += __shfl_xor(s, 32, 64);
    const float inv = 1.0f / s;
#pragma unroll
    for (int r = 0; r < 4; ++r) {
      const float invr = __shfl(inv, quad * 4 + r, 64);
      const int qr = qb + mi * 16 + quad * 4 + r;
      bf16_t* yp = y + ((size_t)b * SEQ + qr) * DM + h * HD;
#pragma unroll
      for (int jn = 0; jn < 4; ++jn)
        yp[jn * 16 + l16] = f2bf(o[mi][jn][r] * invr);
    }
  }
#undef ISSUE
}

extern "C" void kernel_launch(void* const* d_in, const int* in_sizes, int n_in,
                              void* d_out, int out_size, void* d_ws, size_t ws_size,
                              hipStream_t stream) {
  const float* x     = (const float*)d_in[0];
  const float* Wqkv  = (const float*)d_in[1];
  const float* Wproj = (const float*)d_in[2];
  float* out = (float*)d_out;
  char* ws = (char*)d_ws;
  // ws layout (72 MiB):
  bf16_t* qkv = (bf16_t*)(ws);                 // 48 MiB (V third unused)
  bf16_t* Wt1 = (bf16_t*)(ws + 50331648);      // 6 MiB
  bf16_t* Wt2 = (bf16_t*)(ws + 56623104);      // 2 MiB
  bf16_t* xb  = (bf16_t*)(ws + 58720256);      // 16 MiB (dead after GEMM1)
  bf16_t* y   = xb;                            // attn output aliases xb
  // d_out scratch: V^T in first 16 MiB, RoPE table in next 512 KiB; both dead
  // before GEMM2 overwrites d_out.
  bf16_t* vt  = (bf16_t*)d_out;
  float2* tab = (float2*)((char*)d_out + 16777216);

  k_prep<<<12544, 256, 0, stream>>>(Wqkv, Wproj, x, Wt1, Wt2, xb, tab);
  k_gemm<1><<<dim3(QKV_W / 128, (BATCH * SEQ) / 128), 256, 0, stream>>>(
      xb, Wt1, qkv, vt, BATCH * SEQ, QKV_W, DM);
  k_ropek<<<4096, 256, 0, stream>>>(qkv, tab);
  k_attn<<<1024, 256, 0, stream>>>(qkv, vt, tab, y);
  k_gemm<0><<<dim3(DM / 128, (BATCH * SEQ) / 128), 256, 0, stream>>>(
      y, Wt2, out, nullptr, BATCH * SEQ, DM, DM);
}

// Round 11
// 246.254 us; speedup vs baseline: 1.0654x; 1.0095x over previous
//
#include <hip/hip_runtime.h>

// Causal self-attention fwd: x(4,2048,1024)fp32, W_qkv(1024,3072), W_proj(1024,1024)
// Pipeline (5 launches): [k_prep: W transposes + x->bf16 + RoPE table]
//   [GEMM1 qkv + fused V-transpose] [k_ropek: K-RoPE in-place, 32MB]
//   [flash attn w/ fused Q-RoPE] [GEMM2 128x64 tiles]
// R6: swapped QK^T + in-register P via cvt_pk_bf16 + permlane swaps (no P LDS).
// R13: K/V LDS 128B rows + XOR swizzle (0 conflicts).
// R14: attn 1024 blocks (1 Q-tile each, longest-first) = 4 blocks/CU -> attn
//   out of top-5. Lesson: this pipeline's kernels are latency-bound; TLP is
//   the lever.
// R15: same lever on GEMM2. Evidence: GEMM2 (ord-164 signature: 16MB y read +
//   32MB fp32 write) took 68.8us = GEMM1's time at 1/3 the FLOPs -> 10% of
//   MFMA peak, pure exposed per-block latency at 2 blocks/CU (512 blocks).
//   k_gemm2: 128x64 tiles -> 1024 blocks = 4/CU, LDS 24KB, acc[4][2]/wave.

#define BATCH 4
#define SEQ   2048
#define DM    1024
#define NH    16
#define HD    64
#define QKV_W 3072

typedef short bf16x8 __attribute__((ext_vector_type(8)));
typedef float f32x4  __attribute__((ext_vector_type(4)));
typedef unsigned u32x4 __attribute__((ext_vector_type(4)));
typedef unsigned short bf16_t;

#define NLT 0.28782313662425575f    // ln(10000)/32

__device__ __forceinline__ unsigned short f2bf(float f) {
  unsigned u = __float_as_uint(f);
  u += 0x7fffu + ((u >> 16) & 1u);   // round-to-nearest-even
  return (unsigned short)(u >> 16);
}
__device__ __forceinline__ float bf2f(unsigned short s) {
  return __uint_as_float((unsigned)s << 16);
}
// async global->LDS, 16B per lane; LDS dest is wave-uniform base + lane*16
__device__ __forceinline__ void gld16(const void* g, void* l) {
  __builtin_amdgcn_global_load_lds(
      (const __attribute__((address_space(1))) unsigned int*)g,
      (__attribute__((address_space(3))) unsigned int*)l, 16, 0, 0);
}
// packed f32x2 -> bf16x2 (RTNE), lo=a hi=b
__device__ __forceinline__ unsigned cvt_pk_bf16(float a, float b) {
  unsigned r;
  asm("v_cvt_pk_bf16_f32 %0, %1, %2" : "=v"(r) : "v"(a), "v"(b));
  return r;
}
// a.rows{2,3} <-> b.rows{0,1}  (rows = 16-lane groups)
__device__ __forceinline__ void permlane32_swap(unsigned& a, unsigned& b) {
  asm("v_permlane32_swap_b32 %0, %1" : "+v"(a), "+v"(b));
}
// a.rows{1,3} <-> b.rows{0,2}
__device__ __forceinline__ void permlane16_swap(unsigned& a, unsigned& b) {
  asm("v_permlane16_swap_b32 %0, %1" : "+v"(a), "+v"(b));
}

// ---- prep: W transposes (fp32->bf16) + x->bf16 + RoPE cos/sin table --------
// blocks [0,3072): Wqkv transpose; [3072,4096): Wproj; [4096,12288): x cvt;
// [12288,12544): tab[s][i] = (cos, sin)(s * 10000^(-i/32)), accurate sincosf.
__global__ __launch_bounds__(256) void k_prep(const float* __restrict__ W1,
                                              const float* __restrict__ W2,
                                              const float* __restrict__ x,
                                              bf16_t* __restrict__ Wt1,
                                              bf16_t* __restrict__ Wt2,
                                              bf16_t* __restrict__ xb,
                                              float2* __restrict__ tab) {
  __shared__ float tile[32][33];
  const int blk = blockIdx.x, tid = threadIdx.x;
  if (blk < 4096) {
    const float* W;
    bf16_t* Wt;
    int N, bx, by;
    if (blk < 3072) { W = W1; Wt = Wt1; N = QKV_W; bx = blk % 96; by = blk / 96; }
    else            { W = W2; Wt = Wt2; N = DM;    bx = (blk - 3072) & 31; by = (blk - 3072) >> 5; }
    const int tx = tid & 31, ty = tid >> 5;   // (32,8)
    const int n0 = bx * 32, k0 = by * 32;
#pragma unroll
    for (int j = 0; j < 4; ++j)
      tile[ty + j * 8][tx] = W[(size_t)(k0 + ty + j * 8) * N + n0 + tx];
    __syncthreads();
#pragma unroll
    for (int j = 0; j < 4; ++j)
      Wt[(size_t)(n0 + ty + j * 8) * DM + k0 + tx] = f2bf(tile[tx][ty + j * 8]);
  } else if (blk < 12288) {
    const int i = ((blk - 4096) * 256 + tid) * 4;
    float4 v = *(const float4*)(x + i);
    unsigned lo = (unsigned)f2bf(v.x) | ((unsigned)f2bf(v.y) << 16);
    unsigned hi = (unsigned)f2bf(v.z) | ((unsigned)f2bf(v.w) << 16);
    *(uint2*)(xb + i) = make_uint2(lo, hi);
  } else {
    const int idx = (blk - 12288) * 256 + tid;   // 0..65535
    const int s = idx >> 5, i = idx & 31;
    const float inv = __expf((float)i * -NLT);
    float sn, cs;
    sincosf((float)s * inv, &sn, &cs);           // accurate
    tab[idx] = make_float2(cs, sn);
  }
}

// ---------------- K-RoPE in place (K section of qkv), table-driven ----------
// 8192 rows x 1024 K-cols bf16 = 16MB; 128 threads/row, bf16x8 (4 pairs) each.
__global__ __launch_bounds__(256) void k_ropek(bf16_t* __restrict__ qkv,
                                               const float2* __restrict__ tab) {
  const int t = blockIdx.x * 256 + threadIdx.x;   // 0..1048575
  const int row = t >> 7;
  const int c = (t & 127) * 8;         // col within K section
  const int i0 = (c & 63) >> 1;        // first pair index in head
  bf16_t* p = qkv + (size_t)row * QKV_W + DM + c;
  bf16x8 v = *(const bf16x8*)p;
  const float2* tq = tab + (size_t)(row & 2047) * 32 + i0;
  bf16x8 r;
#pragma unroll
  for (int k = 0; k < 4; ++k) {
    const float2 cs = tq[k];
    const float e = bf2f((unsigned short)v[2 * k]);
    const float o = bf2f((unsigned short)v[2 * k + 1]);
    r[2 * k]     = (short)f2bf(e * cs.x - o * cs.y);
    r[2 * k + 1] = (short)f2bf(e * cs.y + o * cs.x);
  }
  *(bf16x8*)p = r;
}

// ---------------- 128x128 bf16 GEMM (2-phase, proven 68us) — GEMM1 ----------
// qkv epilogue: cols<2048 (Q,K) bf16 row-major; cols>=2048 (V) -> vt packed.
__global__ __launch_bounds__(256) void k_gemm(const bf16_t* __restrict__ A,
                                              const bf16_t* __restrict__ Bt,
                                              bf16_t* __restrict__ Cout,
                                              bf16_t* __restrict__ vt,
                                              int M, int N, int K) {
  __shared__ __align__(16) short As[128 * 64];
  __shared__ __align__(16) short Bs[128 * 64];
  const int tid = threadIdx.x;
  const int wave = tid >> 6, lane = tid & 63;
  const int quad = lane >> 4, l16 = lane & 15;
  const int wm = (wave >> 1) * 64, wn = (wave & 1) * 64;
  const int bm = blockIdx.y * 128, bn = blockIdx.x * 128;

  f32x4 acc[4][4];
#pragma unroll
  for (int i = 0; i < 4; ++i)
#pragma unroll
    for (int j = 0; j < 4; ++j) acc[i][j] = f32x4{0.f, 0.f, 0.f, 0.f};

  const int srow = tid >> 3;                       // 0..31
  const int sg   = (tid & 7) ^ (srow & 7);         // swizzled source granule
  const bf16_t* Ap = A  + (size_t)(bm + srow) * K + sg * 8;
  const bf16_t* Bp = Bt + (size_t)(bn + srow) * K + sg * 8;
  short* Ad = As + tid * 8;
  short* Bd = Bs + tid * 8;

  for (int k0 = 0; k0 < K; k0 += 64) {
    __syncthreads();
#pragma unroll
    for (int pp = 0; pp < 4; ++pp) {
      gld16(Ap + (size_t)(pp * 32) * K + k0, Ad + pp * 2048);
      gld16(Bp + (size_t)(pp * 32) * K + k0, Bd + pp * 2048);
    }
    __syncthreads();
#pragma unroll
    for (int ks = 0; ks < 2; ++ks) {
      bf16x8 af[4], bfr[4];
#pragma unroll
      for (int i = 0; i < 4; ++i)
        af[i] = *(const bf16x8*)&As[(wm + i * 16 + l16) * 64 +
                                    (((ks * 4 + quad) ^ (l16 & 7)) << 3)];
#pragma unroll
      for (int j = 0; j < 4; ++j)
        bfr[j] = *(const bf16x8*)&Bs[(wn + j * 16 + l16) * 64 +
                                     (((ks * 4 + quad) ^ (l16 & 7)) << 3)];
#pragma unroll
      for (int i = 0; i < 4; ++i)
#pragma unroll
        for (int j = 0; j < 4; ++j)
          acc[i][j] = __builtin_amdgcn_mfma_f32_16x16x32_bf16(af[i], bfr[j], acc[i][j], 0, 0, 0);
    }
  }
  // C row = quad*4+reg, col = l16 (verified mapping)
#pragma unroll
  for (int i = 0; i < 4; ++i)
#pragma unroll
    for (int j = 0; j < 4; ++j) {
      const int col = bn + wn + j * 16 + l16;
      const int row0 = bm + wm + i * 16 + quad * 4;
      if (col >= 2048) {
        const int d = col - 2048;
        const int hh = d >> 6, dd = d & 63;
        const int bb = row0 >> 11, ss = row0 & 2047;
        ushort4 pk;
        pk.x = f2bf(acc[i][j][0]); pk.y = f2bf(acc[i][j][1]);
        pk.z = f2bf(acc[i][j][2]); pk.w = f2bf(acc[i][j][3]);
        *(ushort4*)(vt + ((size_t)((bb * NH + hh) * HD + dd)) * SEQ + ss) = pk;
      } else {
#pragma unroll
        for (int r = 0; r < 4; ++r)
          Cout[(size_t)(row0 + r) * N + col] = f2bf(acc[i][j][r]);
      }
    }
}

// ---------------- GEMM2: out(fp32) = y * Wt2^T, 128x64 tiles ----------------
// R15: 1024 blocks (dim3(16,64)) = 4 blocks/CU to hide per-block load latency.
// 4 waves 2Mx2N (wave tile 64x32, acc[4][2]); LDS 24KB; same proven swizzle.
__global__ __launch_bounds__(256, 4) void k_gemm2(const bf16_t* __restrict__ A,
                                                  const bf16_t* __restrict__ Bt,
                                                  float* __restrict__ Cout,
                                                  int M, int N, int K) {
  __shared__ __align__(16) short As[128 * 64];
  __shared__ __align__(16) short Bs[64 * 64];
  const int tid = threadIdx.x;
  const int wave = tid >> 6, lane = tid & 63;
  const int quad = lane >> 4, l16 = lane & 15;
  const int wm = (wave >> 1) * 64, wn = (wave & 1) * 32;
  const int bm = blockIdx.y * 128, bn = blockIdx.x * 64;

  f32x4 acc[4][2];
#pragma unroll
  for (int i = 0; i < 4; ++i)
#pragma unroll
    for (int j = 0; j < 2; ++j) acc[i][j] = f32x4{0.f, 0.f, 0.f, 0.f};

  const int srow = tid >> 3;                       // 0..31
  const int sg   = (tid & 7) ^ (srow & 7);         // swizzled source granule
  const bf16_t* Ap = A  + (size_t)(bm + srow) * K + sg * 8;
  const bf16_t* Bp = Bt + (size_t)(bn + srow) * K + sg * 8;
  short* Ad = As + tid * 8;
  short* Bd = Bs + tid * 8;

  for (int k0 = 0; k0 < K; k0 += 64) {
    __syncthreads();
#pragma unroll
    for (int pp = 0; pp < 4; ++pp)
      gld16(Ap + (size_t)(pp * 32) * K + k0, Ad + pp * 2048);
#pragma unroll
    for (int pp = 0; pp < 2; ++pp)
      gld16(Bp + (size_t)(pp * 32) * K + k0, Bd + pp * 2048);
    __syncthreads();
#pragma unroll
    for (int ks = 0; ks < 2; ++ks) {
      bf16x8 af[4], bfr[2];
#pragma unroll
      for (int i = 0; i < 4; ++i)
        af[i] = *(const bf16x8*)&As[(wm + i * 16 + l16) * 64 +
                                    (((ks * 4 + quad) ^ (l16 & 7)) << 3)];
#pragma unroll
      for (int j = 0; j < 2; ++j)
        bfr[j] = *(const bf16x8*)&Bs[(wn + j * 16 + l16) * 64 +
                                     (((ks * 4 + quad) ^ (l16 & 7)) << 3)];
#pragma unroll
      for (int i = 0; i < 4; ++i)
#pragma unroll
        for (int j = 0; j < 2; ++j)
          acc[i][j] = __builtin_amdgcn_mfma_f32_16x16x32_bf16(af[i], bfr[j], acc[i][j], 0, 0, 0);
    }
  }
#pragma unroll
  for (int i = 0; i < 4; ++i)
#pragma unroll
    for (int j = 0; j < 2; ++j) {
      const int col = bn + wn + j * 16 + l16;
      const int row0 = bm + wm + i * 16 + quad * 4;
#pragma unroll
      for (int r = 0; r < 4; ++r)
        Cout[(size_t)(row0 + r) * N + col] = acc[i][j][r];
    }
}

// ---------------- flash attention ----------------
// R14: 1024 blocks, ONE 128-row Q-tile each (4 waves x 32q), longest-first
// (qt = 15 - blk/64) for load balance; 4+ blocks/CU. KV dbuf + cross-iter
// prefetch, 1 barrier/iter. Q pre-scaled by 0.125*log2e => p = exp2(s').
// Q-RoPE fused via table; pairs in-lane in bf16x8.
// Swapped QK^T: S^T = mfma(K, Q) so each lane holds P[q=l16][k=jn*16+quad*4+r];
// PV A-frags built in-register via cvt_pk + permlane32/16 swaps — no P LDS.
// K/V tiles [64][64] shorts (128B rows) + slot^(l16&7) XOR swizzle (0-conflict).
#define QSCALE 0.18033688011112042f   // 0.125 * log2(e)
__global__ __launch_bounds__(256, 4) void k_attn(const bf16_t* __restrict__ qkv,
                                                 const bf16_t* __restrict__ vt,
                                                 const float2* __restrict__ tab,
                                                 bf16_t* __restrict__ y) {
  __shared__ __align__(16) short Kb[2][64 * 64];   // [buf][kv-row][k-dim]
  __shared__ __align__(16) short Vb[2][64 * 64];   // [buf][d-row][kv-dim]
  const int tid = threadIdx.x;
  const int lane = tid & 63;
  const int quad = lane >> 4, l16 = lane & 15;
  const int wave = tid >> 6;
  const int xs = l16 & 7;
  const int l = blockIdx.x;
  const int qt = 15 - (l >> 6);                  // longest tiles first
  const int hb = l & 63;
  const int h = hb & 15, b = hb >> 4;
  const size_t bbase = (size_t)b * SEQ * QKV_W;
  // staging: thread t -> LDS row (t>>3) and (t>>3)+32, slot t&7;
  // source granule pre-swizzled: sg = (t&7) ^ ((t>>3)&7)  [(r+32)&7 == r&7]
  const int sr8 = tid >> 3;                      // 0..31
  const int sg  = (tid & 7) ^ (sr8 & 7);
  const bf16_t* kbase = qkv + bbase + (size_t)sr8 * QKV_W + DM + h * HD + sg * 8;
  const bf16_t* vbase = vt + ((size_t)(b * NH + h) * HD + sr8) * SEQ + sg * 8;

#define ISSUE(kv0, buf)                                                   \
  do {                                                                    \
    gld16(kbase + (size_t)(kv0) * QKV_W,        &Kb[buf][tid * 8]);       \
    gld16(kbase + (size_t)((kv0) + 32) * QKV_W, &Kb[buf][2048 + tid * 8]);\
    gld16(vbase + (kv0),                        &Vb[buf][tid * 8]);       \
    gld16(vbase + (size_t)32 * SEQ + (kv0),     &Vb[buf][2048 + tid * 8]);\
  } while (0)

  int bufp = 0;
  ISSUE(0, 0);
  const int qb = qt * 128 + wave * 32;           // wave's first q row
  // load Q fragments; apply RoPE (in-lane pairs, table) + QSCALE in fp32
  bf16x8 aq[2][2];
#pragma unroll
  for (int mi = 0; mi < 2; ++mi) {
    const float2* tq = tab + (size_t)(qb + mi * 16 + l16) * 32;
#pragma unroll
    for (int kk = 0; kk < 2; ++kk) {
      const bf16_t* qp = qkv + bbase + (size_t)(qb + mi * 16 + l16) * QKV_W +
                         h * HD + kk * 32 + quad * 8;
      bf16x8 raw = *(const bf16x8*)qp;
      bf16x8 sc;
#pragma unroll
      for (int t = 0; t < 4; ++t) {
        const float2 cs = tq[kk * 16 + quad * 4 + t];
        const float e = bf2f((unsigned short)raw[2 * t]);
        const float o = bf2f((unsigned short)raw[2 * t + 1]);
        sc[2 * t]     = (short)f2bf((e * cs.x - o * cs.y) * QSCALE);
        sc[2 * t + 1] = (short)f2bf((e * cs.y + o * cs.x) * QSCALE);
      }
      aq[mi][kk] = sc;
    }
  }
  f32x4 o[2][4];
  float lsum[2];
#pragma unroll
  for (int mi = 0; mi < 2; ++mi) {
    lsum[mi] = 0.f;
#pragma unroll
    for (int jn = 0; jn < 4; ++jn) o[mi][jn] = f32x4{0.f, 0.f, 0.f, 0.f};
  }
  const int qr0 = qb + l16;                      // this lane's q row (mi=0)

  const int jmax = 2 * qt + 1;
  for (int j = 0; j <= jmax; ++j) {
    const int kv0 = j * 64;
    __syncthreads();   // drains this buf's loads; WAR-protects prefetch target
    if (j < jmax) ISSUE(kv0 + 64, bufp ^ 1);
    if (kv0 <= qb + 31) {  // else: fully masked for this wave — skip
      const bool needmask = (kv0 + 63 > qb);
      const short* Kc = &Kb[bufp][0];
      const short* Vc = &Vb[bufp][0];

      // S^T frags: st[jn][mi]; row = kv (jn*16+quad*4+r), col = q (mi*16+l16)
      f32x4 st[4][2];
#pragma unroll
      for (int jn = 0; jn < 4; ++jn) {
        const int krow = (jn * 16 + l16) * 64;
        bf16x8 ak0 = *(const bf16x8*)&Kc[krow + ((quad ^ xs) << 3)];
        bf16x8 ak1 = *(const bf16x8*)&Kc[krow + (((4 + quad) ^ xs) << 3)];
#pragma unroll
        for (int mi = 0; mi < 2; ++mi) {
          f32x4 s4 = f32x4{0.f, 0.f, 0.f, 0.f};
          s4 = __builtin_amdgcn_mfma_f32_16x16x32_bf16(ak0, aq[mi][0], s4, 0, 0, 0);
          s4 = __builtin_amdgcn_mfma_f32_16x16x32_bf16(ak1, aq[mi][1], s4, 0, 0, 0);
          st[jn][mi] = s4;
        }
      }
      // p = exp2(s'); mask near diagonal; pack r-pairs to bf16x2
      unsigned pk[4][2][2];
#pragma unroll
      for (int jn = 0; jn < 4; ++jn)
#pragma unroll
        for (int mi = 0; mi < 2; ++mi) {
          const int kvb = kv0 + jn * 16 + quad * 4;
          const int qr = qr0 + mi * 16;
          float e[4];
#pragma unroll
          for (int r = 0; r < 4; ++r) {
            float v = __builtin_amdgcn_exp2f(st[jn][mi][r]);
            if (needmask) v = (kvb + r <= qr) ? v : 0.f;
            lsum[mi] += v;
            e[r] = v;
          }
          pk[jn][mi][0] = cvt_pk_bf16(e[0], e[1]);
          pk[jn][mi][1] = cvt_pk_bf16(e[2], e[3]);
        }
      // redistribute across quads -> PV A-frags ap[mi][ks]
      bf16x8 ap[2][2];
#pragma unroll
      for (int mi = 0; mi < 2; ++mi)
#pragma unroll
        for (int ks = 0; ks < 2; ++ks) {
          unsigned a0 = pk[2 * ks][mi][0], b0 = pk[2 * ks + 1][mi][0];
          permlane32_swap(a0, b0);
          permlane16_swap(a0, b0);
          unsigned a1 = pk[2 * ks][mi][1], b1 = pk[2 * ks + 1][mi][1];
          permlane32_swap(a1, b1);
          permlane16_swap(a1, b1);
          union { u32x4 u; bf16x8 s; } f;
          f.u = (u32x4){a0, a1, b0, b1};
          ap[mi][ks] = f.s;
        }
      // O += P V  (V frags shared across mi)
#pragma unroll
      for (int ks = 0; ks < 2; ++ks) {
#pragma unroll
        for (int jn = 0; jn < 4; ++jn) {
          bf16x8 bv = *(const bf16x8*)&Vc[(jn * 16 + l16) * 64 +
                                          (((ks * 4 + quad) ^ xs) << 3)];
          o[0][jn] = __builtin_amdgcn_mfma_f32_16x16x32_bf16(ap[0][ks], bv, o[0][jn], 0, 0, 0);
          o[1][jn] = __builtin_amdgcn_mfma_f32_16x16x32_bf16(ap[1][ks], bv, o[1][jn], 0, 0, 0);
        }
      }
    }
    bufp ^= 1;
  }
  // normalize + write: lane holds full row-sum for q = l16 (+mi*16) after
  // quad-reduce; redistribute inv to output rows (quad*4+r) via shfl.
#pragma unroll
  for (int mi = 0; mi < 2; ++mi) {
    float s = lsum[mi];
    s += __shfl_xor(s, 16, 64);
    s += __shfl_xor(s, 32, 64);
    const float inv = 1.0f / s;
#pragma unroll
    for (int r = 0; r < 4; ++r) {
      const float invr = __shfl(inv, quad * 4 + r, 64);
      const int qr = qb + mi * 16 + quad * 4 + r;
      bf16_t* yp = y + ((size_t)b * SEQ + qr) * DM + h * HD;
#pragma unroll
      for (int jn = 0; jn < 4; ++jn)
        yp[jn * 16 + l16] = f2bf(o[mi][jn][r] * invr);
    }
  }
#undef ISSUE
}

extern "C" void kernel_launch(void* const* d_in, const int* in_sizes, int n_in,
                              void* d_out, int out_size, void* d_ws, size_t ws_size,
                              hipStream_t stream) {
  const float* x     = (const float*)d_in[0];
  const float* Wqkv  = (const float*)d_in[1];
  const float* Wproj = (const float*)d_in[2];
  float* out = (float*)d_out;
  char* ws = (char*)d_ws;
  // ws layout (72 MiB):
  bf16_t* qkv = (bf16_t*)(ws);                 // 48 MiB (V third unused)
  bf16_t* Wt1 = (bf16_t*)(ws + 50331648);      // 6 MiB
  bf16_t* Wt2 = (bf16_t*)(ws + 56623104);      // 2 MiB
  bf16_t* xb  = (bf16_t*)(ws + 58720256);      // 16 MiB (dead after GEMM1)
  bf16_t* y   = xb;                            // attn output aliases xb
  // d_out scratch: V^T in first 16 MiB, RoPE table in next 512 KiB; both dead
  // before GEMM2 overwrites d_out.
  bf16_t* vt  = (bf16_t*)d_out;
  float2* tab = (float2*)((char*)d_out + 16777216);

  k_prep<<<12544, 256, 0, stream>>>(Wqkv, Wproj, x, Wt1, Wt2, xb, tab);
  k_gemm<<<dim3(QKV_W / 128, (BATCH * SEQ) / 128), 256, 0, stream>>>(
      xb, Wt1, qkv, vt, BATCH * SEQ, QKV_W, DM);
  k_ropek<<<4096, 256, 0, stream>>>(qkv, tab);
  k_attn<<<1024, 256, 0, stream>>>(qkv, vt, tab, y);
  k_gemm2<<<dim3(DM / 64, (BATCH * SEQ) / 128), 256, 0, stream>>>(
      y, Wt2, out, BATCH * SEQ, DM, DM);
}

// Round 12
// 241.508 us; speedup vs baseline: 1.0863x; 1.0196x over previous
//
#include <hip/hip_runtime.h>

// Causal self-attention fwd: x(4,2048,1024)fp32, W_qkv(1024,3072), W_proj(1024,1024)
// Pipeline (5 launches): [k_prep: W transposes + x->bf16 + RoPE table]
//   [GEMM1 qkv + fused V-transpose] [k_ropek: K-RoPE in-place, 32MB]
//   [flash attn w/ fused Q-RoPE] [GEMM2 128x64 tiles]
// R6: swapped QK^T + in-register P via cvt_pk_bf16 + permlane swaps (no P LDS).
// R13: K/V LDS 128B rows + XOR swizzle (0 conflicts).
// R14/R15: latency-bound kernels want TLP: attn 1024 blocks (1 Q-tile each),
//   GEMM2 128x64 tiles -> 1024 blocks = 4/CU. Both left the top-5.
// R16: XCD 2D chunking on both GEMMs. Evidence: GEMM1 FETCH 71.9MB vs 22MB
//   floor (3.3x) -- consecutive blocks sharing an A-panel round-robin across
//   8 private L2s. Chunk 12bx x 16by per XCD (A 4MB + B 3MB, L2-resident);
//   GEMM2 8bx x 16by. Mechanism: fewer HBM misses shorten the per-iter
//   vmcnt(0) barrier drain (L2 ~200cyc vs HBM ~900cyc), the 2-phase
//   structure's critical path. attn grid already XCD-coherent (l%8 = hb%8).

#define BATCH 4
#define SEQ   2048
#define DM    1024
#define NH    16
#define HD    64
#define QKV_W 3072

typedef short bf16x8 __attribute__((ext_vector_type(8)));
typedef float f32x4  __attribute__((ext_vector_type(4)));
typedef unsigned u32x4 __attribute__((ext_vector_type(4)));
typedef unsigned short bf16_t;

#define NLT 0.28782313662425575f    // ln(10000)/32

__device__ __forceinline__ unsigned short f2bf(float f) {
  unsigned u = __float_as_uint(f);
  u += 0x7fffu + ((u >> 16) & 1u);   // round-to-nearest-even
  return (unsigned short)(u >> 16);
}
__device__ __forceinline__ float bf2f(unsigned short s) {
  return __uint_as_float((unsigned)s << 16);
}
// async global->LDS, 16B per lane; LDS dest is wave-uniform base + lane*16
__device__ __forceinline__ void gld16(const void* g, void* l) {
  __builtin_amdgcn_global_load_lds(
      (const __attribute__((address_space(1))) unsigned int*)g,
      (__attribute__((address_space(3))) unsigned int*)l, 16, 0, 0);
}
// packed f32x2 -> bf16x2 (RTNE), lo=a hi=b
__device__ __forceinline__ unsigned cvt_pk_bf16(float a, float b) {
  unsigned r;
  asm("v_cvt_pk_bf16_f32 %0, %1, %2" : "=v"(r) : "v"(a), "v"(b));
  return r;
}
// a.rows{2,3} <-> b.rows{0,1}  (rows = 16-lane groups)
__device__ __forceinline__ void permlane32_swap(unsigned& a, unsigned& b) {
  asm("v_permlane32_swap_b32 %0, %1" : "+v"(a), "+v"(b));
}
// a.rows{1,3} <-> b.rows{0,2}
__device__ __forceinline__ void permlane16_swap(unsigned& a, unsigned& b) {
  asm("v_permlane16_swap_b32 %0, %1" : "+v"(a), "+v"(b));
}

// ---- prep: W transposes (fp32->bf16) + x->bf16 + RoPE cos/sin table --------
// blocks [0,3072): Wqkv transpose; [3072,4096): Wproj; [4096,12288): x cvt;
// [12288,12544): tab[s][i] = (cos, sin)(s * 10000^(-i/32)), accurate sincosf.
__global__ __launch_bounds__(256) void k_prep(const float* __restrict__ W1,
                                              const float* __restrict__ W2,
                                              const float* __restrict__ x,
                                              bf16_t* __restrict__ Wt1,
                                              bf16_t* __restrict__ Wt2,
                                              bf16_t* __restrict__ xb,
                                              float2* __restrict__ tab) {
  __shared__ float tile[32][33];
  const int blk = blockIdx.x, tid = threadIdx.x;
  if (blk < 4096) {
    const float* W;
    bf16_t* Wt;
    int N, bx, by;
    if (blk < 3072) { W = W1; Wt = Wt1; N = QKV_W; bx = blk % 96; by = blk / 96; }
    else            { W = W2; Wt = Wt2; N = DM;    bx = (blk - 3072) & 31; by = (blk - 3072) >> 5; }
    const int tx = tid & 31, ty = tid >> 5;   // (32,8)
    const int n0 = bx * 32, k0 = by * 32;
#pragma unroll
    for (int j = 0; j < 4; ++j)
      tile[ty + j * 8][tx] = W[(size_t)(k0 + ty + j * 8) * N + n0 + tx];
    __syncthreads();
#pragma unroll
    for (int j = 0; j < 4; ++j)
      Wt[(size_t)(n0 + ty + j * 8) * DM + k0 + tx] = f2bf(tile[tx][ty + j * 8]);
  } else if (blk < 12288) {
    const int i = ((blk - 4096) * 256 + tid) * 4;
    float4 v = *(const float4*)(x + i);
    unsigned lo = (unsigned)f2bf(v.x) | ((unsigned)f2bf(v.y) << 16);
    unsigned hi = (unsigned)f2bf(v.z) | ((unsigned)f2bf(v.w) << 16);
    *(uint2*)(xb + i) = make_uint2(lo, hi);
  } else {
    const int idx = (blk - 12288) * 256 + tid;   // 0..65535
    const int s = idx >> 5, i = idx & 31;
    const float inv = __expf((float)i * -NLT);
    float sn, cs;
    sincosf((float)s * inv, &sn, &cs);           // accurate
    tab[idx] = make_float2(cs, sn);
  }
}

// ---------------- K-RoPE in place (K section of qkv), table-driven ----------
// 8192 rows x 1024 K-cols bf16 = 16MB; 128 threads/row, bf16x8 (4 pairs) each.
__global__ __launch_bounds__(256) void k_ropek(bf16_t* __restrict__ qkv,
                                               const float2* __restrict__ tab) {
  const int t = blockIdx.x * 256 + threadIdx.x;   // 0..1048575
  const int row = t >> 7;
  const int c = (t & 127) * 8;         // col within K section
  const int i0 = (c & 63) >> 1;        // first pair index in head
  bf16_t* p = qkv + (size_t)row * QKV_W + DM + c;
  bf16x8 v = *(const bf16x8*)p;
  const float2* tq = tab + (size_t)(row & 2047) * 32 + i0;
  bf16x8 r;
#pragma unroll
  for (int k = 0; k < 4; ++k) {
    const float2 cs = tq[k];
    const float e = bf2f((unsigned short)v[2 * k]);
    const float o = bf2f((unsigned short)v[2 * k + 1]);
    r[2 * k]     = (short)f2bf(e * cs.x - o * cs.y);
    r[2 * k + 1] = (short)f2bf(e * cs.y + o * cs.x);
  }
  *(bf16x8*)p = r;
}

// ---------------- 128x128 bf16 GEMM (2-phase) — GEMM1 ----------------
// R16: 1D grid 1536, XCD 2D chunking: xcd = bid&7 owns a 12bx x 16by chunk
// (A 16 panels = 4MB + B 12 panels = 3MB, both ~L2-resident per XCD).
// qkv epilogue: cols<2048 (Q,K) bf16 row-major; cols>=2048 (V) -> vt packed.
__global__ __launch_bounds__(256) void k_gemm(const bf16_t* __restrict__ A,
                                              const bf16_t* __restrict__ Bt,
                                              bf16_t* __restrict__ Cout,
                                              bf16_t* __restrict__ vt,
                                              int M, int N, int K) {
  __shared__ __align__(16) short As[128 * 64];
  __shared__ __align__(16) short Bs[128 * 64];
  const int tid = threadIdx.x;
  const int wave = tid >> 6, lane = tid & 63;
  const int quad = lane >> 4, l16 = lane & 15;
  const int wm = (wave >> 1) * 64, wn = (wave & 1) * 64;
  // XCD chunking: 8 XCDs = 2 x-chunks (12 bx) x 4 y-chunks (16 by)
  const int bid = (int)blockIdx.x;
  const int xcd = bid & 7, w = bid >> 3;          // w in [0,192)
  const int bx = (xcd & 1) * 12 + w % 12;
  const int by = (xcd >> 1) * 16 + w / 12;
  const int bm = by * 128, bn = bx * 128;

  f32x4 acc[4][4];
#pragma unroll
  for (int i = 0; i < 4; ++i)
#pragma unroll
    for (int j = 0; j < 4; ++j) acc[i][j] = f32x4{0.f, 0.f, 0.f, 0.f};

  const int srow = tid >> 3;                       // 0..31
  const int sg   = (tid & 7) ^ (srow & 7);         // swizzled source granule
  const bf16_t* Ap = A  + (size_t)(bm + srow) * K + sg * 8;
  const bf16_t* Bp = Bt + (size_t)(bn + srow) * K + sg * 8;
  short* Ad = As + tid * 8;
  short* Bd = Bs + tid * 8;

  for (int k0 = 0; k0 < K; k0 += 64) {
    __syncthreads();
#pragma unroll
    for (int pp = 0; pp < 4; ++pp) {
      gld16(Ap + (size_t)(pp * 32) * K + k0, Ad + pp * 2048);
      gld16(Bp + (size_t)(pp * 32) * K + k0, Bd + pp * 2048);
    }
    __syncthreads();
#pragma unroll
    for (int ks = 0; ks < 2; ++ks) {
      bf16x8 af[4], bfr[4];
#pragma unroll
      for (int i = 0; i < 4; ++i)
        af[i] = *(const bf16x8*)&As[(wm + i * 16 + l16) * 64 +
                                    (((ks * 4 + quad) ^ (l16 & 7)) << 3)];
#pragma unroll
      for (int j = 0; j < 4; ++j)
        bfr[j] = *(const bf16x8*)&Bs[(wn + j * 16 + l16) * 64 +
                                     (((ks * 4 + quad) ^ (l16 & 7)) << 3)];
#pragma unroll
      for (int i = 0; i < 4; ++i)
#pragma unroll
        for (int j = 0; j < 4; ++j)
          acc[i][j] = __builtin_amdgcn_mfma_f32_16x16x32_bf16(af[i], bfr[j], acc[i][j], 0, 0, 0);
    }
  }
  // C row = quad*4+reg, col = l16 (verified mapping)
#pragma unroll
  for (int i = 0; i < 4; ++i)
#pragma unroll
    for (int j = 0; j < 4; ++j) {
      const int col = bn + wn + j * 16 + l16;
      const int row0 = bm + wm + i * 16 + quad * 4;
      if (col >= 2048) {
        const int d = col - 2048;
        const int hh = d >> 6, dd = d & 63;
        const int bb = row0 >> 11, ss = row0 & 2047;
        ushort4 pk;
        pk.x = f2bf(acc[i][j][0]); pk.y = f2bf(acc[i][j][1]);
        pk.z = f2bf(acc[i][j][2]); pk.w = f2bf(acc[i][j][3]);
        *(ushort4*)(vt + ((size_t)((bb * NH + hh) * HD + dd)) * SEQ + ss) = pk;
      } else {
#pragma unroll
        for (int r = 0; r < 4; ++r)
          Cout[(size_t)(row0 + r) * N + col] = f2bf(acc[i][j][r]);
      }
    }
}

// ---------------- GEMM2: out(fp32) = y * Wt2^T, 128x64 tiles ----------------
// R15: 1024 blocks = 4 blocks/CU. R16: XCD chunking 8bx x 16by per XCD
// (A 16 panels = 4MB + B 8 panels = 1MB per-XCD working set).
__global__ __launch_bounds__(256, 4) void k_gemm2(const bf16_t* __restrict__ A,
                                                  const bf16_t* __restrict__ Bt,
                                                  float* __restrict__ Cout,
                                                  int M, int N, int K) {
  __shared__ __align__(16) short As[128 * 64];
  __shared__ __align__(16) short Bs[64 * 64];
  const int tid = threadIdx.x;
  const int wave = tid >> 6, lane = tid & 63;
  const int quad = lane >> 4, l16 = lane & 15;
  const int wm = (wave >> 1) * 64, wn = (wave & 1) * 32;
  const int bid = (int)blockIdx.x;
  const int xcd = bid & 7, w = bid >> 3;          // w in [0,128)
  const int bx = (xcd & 1) * 8 + (w & 7);
  const int by = (xcd >> 1) * 16 + (w >> 3);
  const int bm = by * 128, bn = bx * 64;

  f32x4 acc[4][2];
#pragma unroll
  for (int i = 0; i < 4; ++i)
#pragma unroll
    for (int j = 0; j < 2; ++j) acc[i][j] = f32x4{0.f, 0.f, 0.f, 0.f};

  const int srow = tid >> 3;                       // 0..31
  const int sg   = (tid & 7) ^ (srow & 7);         // swizzled source granule
  const bf16_t* Ap = A  + (size_t)(bm + srow) * K + sg * 8;
  const bf16_t* Bp = Bt + (size_t)(bn + srow) * K + sg * 8;
  short* Ad = As + tid * 8;
  short* Bd = Bs + tid * 8;

  for (int k0 = 0; k0 < K; k0 += 64) {
    __syncthreads();
#pragma unroll
    for (int pp = 0; pp < 4; ++pp)
      gld16(Ap + (size_t)(pp * 32) * K + k0, Ad + pp * 2048);
#pragma unroll
    for (int pp = 0; pp < 2; ++pp)
      gld16(Bp + (size_t)(pp * 32) * K + k0, Bd + pp * 2048);
    __syncthreads();
#pragma unroll
    for (int ks = 0; ks < 2; ++ks) {
      bf16x8 af[4], bfr[2];
#pragma unroll
      for (int i = 0; i < 4; ++i)
        af[i] = *(const bf16x8*)&As[(wm + i * 16 + l16) * 64 +
                                    (((ks * 4 + quad) ^ (l16 & 7)) << 3)];
#pragma unroll
      for (int j = 0; j < 2; ++j)
        bfr[j] = *(const bf16x8*)&Bs[(wn + j * 16 + l16) * 64 +
                                     (((ks * 4 + quad) ^ (l16 & 7)) << 3)];
#pragma unroll
      for (int i = 0; i < 4; ++i)
#pragma unroll
        for (int j = 0; j < 2; ++j)
          acc[i][j] = __builtin_amdgcn_mfma_f32_16x16x32_bf16(af[i], bfr[j], acc[i][j], 0, 0, 0);
    }
  }
#pragma unroll
  for (int i = 0; i < 4; ++i)
#pragma unroll
    for (int j = 0; j < 2; ++j) {
      const int col = bn + wn + j * 16 + l16;
      const int row0 = bm + wm + i * 16 + quad * 4;
#pragma unroll
      for (int r = 0; r < 4; ++r)
        Cout[(size_t)(row0 + r) * N + col] = acc[i][j][r];
    }
}

// ---------------- flash attention ----------------
// R14: 1024 blocks, ONE 128-row Q-tile each (4 waves x 32q), longest-first
// (qt = 15 - blk/64) for load balance; 4+ blocks/CU. KV dbuf + cross-iter
// prefetch, 1 barrier/iter. Q pre-scaled by 0.125*log2e => p = exp2(s').
// Q-RoPE fused via table; pairs in-lane in bf16x8.
// Swapped QK^T: S^T = mfma(K, Q) so each lane holds P[q=l16][k=jn*16+quad*4+r];
// PV A-frags built in-register via cvt_pk + permlane32/16 swaps — no P LDS.
// K/V tiles [64][64] shorts (128B rows) + slot^(l16&7) XOR swizzle (0-conflict).
#define QSCALE 0.18033688011112042f   // 0.125 * log2(e)
__global__ __launch_bounds__(256, 4) void k_attn(const bf16_t* __restrict__ qkv,
                                                 const bf16_t* __restrict__ vt,
                                                 const float2* __restrict__ tab,
                                                 bf16_t* __restrict__ y) {
  __shared__ __align__(16) short Kb[2][64 * 64];   // [buf][kv-row][k-dim]
  __shared__ __align__(16) short Vb[2][64 * 64];   // [buf][d-row][kv-dim]
  const int tid = threadIdx.x;
  const int lane = tid & 63;
  const int quad = lane >> 4, l16 = lane & 15;
  const int wave = tid >> 6;
  const int xs = l16 & 7;
  const int l = blockIdx.x;
  const int qt = 15 - (l >> 6);                  // longest tiles first
  const int hb = l & 63;
  const int h = hb & 15, b = hb >> 4;
  const size_t bbase = (size_t)b * SEQ * QKV_W;
  // staging: thread t -> LDS row (t>>3) and (t>>3)+32, slot t&7;
  // source granule pre-swizzled: sg = (t&7) ^ ((t>>3)&7)  [(r+32)&7 == r&7]
  const int sr8 = tid >> 3;                      // 0..31
  const int sg  = (tid & 7) ^ (sr8 & 7);
  const bf16_t* kbase = qkv + bbase + (size_t)sr8 * QKV_W + DM + h * HD + sg * 8;
  const bf16_t* vbase = vt + ((size_t)(b * NH + h) * HD + sr8) * SEQ + sg * 8;

#define ISSUE(kv0, buf)                                                   \
  do {                                                                    \
    gld16(kbase + (size_t)(kv0) * QKV_W,        &Kb[buf][tid * 8]);       \
    gld16(kbase + (size_t)((kv0) + 32) * QKV_W, &Kb[buf][2048 + tid * 8]);\
    gld16(vbase + (kv0),                        &Vb[buf][tid * 8]);       \
    gld16(vbase + (size_t)32 * SEQ + (kv0),     &Vb[buf][2048 + tid * 8]);\
  } while (0)

  int bufp = 0;
  ISSUE(0, 0);
  const int qb = qt * 128 + wave * 32;           // wave's first q row
  // load Q fragments; apply RoPE (in-lane pairs, table) + QSCALE in fp32
  bf16x8 aq[2][2];
#pragma unroll
  for (int mi = 0; mi < 2; ++mi) {
    const float2* tq = tab + (size_t)(qb + mi * 16 + l16) * 32;
#pragma unroll
    for (int kk = 0; kk < 2; ++kk) {
      const bf16_t* qp = qkv + bbase + (size_t)(qb + mi * 16 + l16) * QKV_W +
                         h * HD + kk * 32 + quad * 8;
      bf16x8 raw = *(const bf16x8*)qp;
      bf16x8 sc;
#pragma unroll
      for (int t = 0; t < 4; ++t) {
        const float2 cs = tq[kk * 16 + quad * 4 + t];
        const float e = bf2f((unsigned short)raw[2 * t]);
        const float o = bf2f((unsigned short)raw[2 * t + 1]);
        sc[2 * t]     = (short)f2bf((e * cs.x - o * cs.y) * QSCALE);
        sc[2 * t + 1] = (short)f2bf((e * cs.y + o * cs.x) * QSCALE);
      }
      aq[mi][kk] = sc;
    }
  }
  f32x4 o[2][4];
  float lsum[2];
#pragma unroll
  for (int mi = 0; mi < 2; ++mi) {
    lsum[mi] = 0.f;
#pragma unroll
    for (int jn = 0; jn < 4; ++jn) o[mi][jn] = f32x4{0.f, 0.f, 0.f, 0.f};
  }
  const int qr0 = qb + l16;                      // this lane's q row (mi=0)

  const int jmax = 2 * qt + 1;
  for (int j = 0; j <= jmax; ++j) {
    const int kv0 = j * 64;
    __syncthreads();   // drains this buf's loads; WAR-protects prefetch target
    if (j < jmax) ISSUE(kv0 + 64, bufp ^ 1);
    if (kv0 <= qb + 31) {  // else: fully masked for this wave — skip
      const bool needmask = (kv0 + 63 > qb);
      const short* Kc = &Kb[bufp][0];
      const short* Vc = &Vb[bufp][0];

      // S^T frags: st[jn][mi]; row = kv (jn*16+quad*4+r), col = q (mi*16+l16)
      f32x4 st[4][2];
#pragma unroll
      for (int jn = 0; jn < 4; ++jn) {
        const int krow = (jn * 16 + l16) * 64;
        bf16x8 ak0 = *(const bf16x8*)&Kc[krow + ((quad ^ xs) << 3)];
        bf16x8 ak1 = *(const bf16x8*)&Kc[krow + (((4 + quad) ^ xs) << 3)];
#pragma unroll
        for (int mi = 0; mi < 2; ++mi) {
          f32x4 s4 = f32x4{0.f, 0.f, 0.f, 0.f};
          s4 = __builtin_amdgcn_mfma_f32_16x16x32_bf16(ak0, aq[mi][0], s4, 0, 0, 0);
          s4 = __builtin_amdgcn_mfma_f32_16x16x32_bf16(ak1, aq[mi][1], s4, 0, 0, 0);
          st[jn][mi] = s4;
        }
      }
      // p = exp2(s'); mask near diagonal; pack r-pairs to bf16x2
      unsigned pk[4][2][2];
#pragma unroll
      for (int jn = 0; jn < 4; ++jn)
#pragma unroll
        for (int mi = 0; mi < 2; ++mi) {
          const int kvb = kv0 + jn * 16 + quad * 4;
          const int qr = qr0 + mi * 16;
          float e[4];
#pragma unroll
          for (int r = 0; r < 4; ++r) {
            float v = __builtin_amdgcn_exp2f(st[jn][mi][r]);
            if (needmask) v = (kvb + r <= qr) ? v : 0.f;
            lsum[mi] += v;
            e[r] = v;
          }
          pk[jn][mi][0] = cvt_pk_bf16(e[0], e[1]);
          pk[jn][mi][1] = cvt_pk_bf16(e[2], e[3]);
        }
      // redistribute across quads -> PV A-frags ap[mi][ks]
      bf16x8 ap[2][2];
#pragma unroll
      for (int mi = 0; mi < 2; ++mi)
#pragma unroll
        for (int ks = 0; ks < 2; ++ks) {
          unsigned a0 = pk[2 * ks][mi][0], b0 = pk[2 * ks + 1][mi][0];
          permlane32_swap(a0, b0);
          permlane16_swap(a0, b0);
          unsigned a1 = pk[2 * ks][mi][1], b1 = pk[2 * ks + 1][mi][1];
          permlane32_swap(a1, b1);
          permlane16_swap(a1, b1);
          union { u32x4 u; bf16x8 s; } f;
          f.u = (u32x4){a0, a1, b0, b1};
          ap[mi][ks] = f.s;
        }
      // O += P V  (V frags shared across mi)
#pragma unroll
      for (int ks = 0; ks < 2; ++ks) {
#pragma unroll
        for (int jn = 0; jn < 4; ++jn) {
          bf16x8 bv = *(const bf16x8*)&Vc[(jn * 16 + l16) * 64 +
                                          (((ks * 4 + quad) ^ xs) << 3)];
          o[0][jn] = __builtin_amdgcn_mfma_f32_16x16x32_bf16(ap[0][ks], bv, o[0][jn], 0, 0, 0);
          o[1][jn] = __builtin_amdgcn_mfma_f32_16x16x32_bf16(ap[1][ks], bv, o[1][jn], 0, 0, 0);
        }
      }
    }
    bufp ^= 1;
  }
  // normalize + write: lane holds full row-sum for q = l16 (+mi*16) after
  // quad-reduce; redistribute inv to output rows (quad*4+r) via shfl.
#pragma unroll
  for (int mi = 0; mi < 2; ++mi) {
    float s = lsum[mi];
    s += __shfl_xor(s, 16, 64);
    s += __shfl_xor(s, 32, 64);
    const float inv = 1.0f / s;
#pragma unroll
    for (int r = 0; r < 4; ++r) {
      const float invr = __shfl(inv, quad * 4 + r, 64);
      const int qr = qb + mi * 16 + quad * 4 + r;
      bf16_t* yp = y + ((size_t)b * SEQ + qr) * DM + h * HD;
#pragma unroll
      for (int jn = 0; jn < 4; ++jn)
        yp[jn * 16 + l16] = f2bf(o[mi][jn][r] * invr);
    }
  }
#undef ISSUE
}

extern "C" void kernel_launch(void* const* d_in, const int* in_sizes, int n_in,
                              void* d_out, int out_size, void* d_ws, size_t ws_size,
                              hipStream_t stream) {
  const float* x     = (const float*)d_in[0];
  const float* Wqkv  = (const float*)d_in[1];
  const float* Wproj = (const float*)d_in[2];
  float* out = (float*)d_out;
  char* ws = (char*)d_ws;
  // ws layout (72 MiB):
  bf16_t* qkv = (bf16_t*)(ws);                 // 48 MiB (V third unused)
  bf16_t* Wt1 = (bf16_t*)(ws + 50331648);      // 6 MiB
  bf16_t* Wt2 = (bf16_t*)(ws + 56623104);      // 2 MiB
  bf16_t* xb  = (bf16_t*)(ws + 58720256);      // 16 MiB (dead after GEMM1)
  bf16_t* y   = xb;                            // attn output aliases xb
  // d_out scratch: V^T in first 16 MiB, RoPE table in next 512 KiB; both dead
  // before GEMM2 overwrites d_out.
  bf16_t* vt  = (bf16_t*)d_out;
  float2* tab = (float2*)((char*)d_out + 16777216);

  k_prep<<<12544, 256, 0, stream>>>(Wqkv, Wproj, x, Wt1, Wt2, xb, tab);
  k_gemm<<<1536, 256, 0, stream>>>(xb, Wt1, qkv, vt, BATCH * SEQ, QKV_W, DM);
  k_ropek<<<4096, 256, 0, stream>>>(qkv, tab);
  k_attn<<<1024, 256, 0, stream>>>(qkv, vt, tab, y);
  k_gemm2<<<1024, 256, 0, stream>>>(y, Wt2, out, BATCH * SEQ, DM, DM);
}

// Round 13
// 238.486 us; speedup vs baseline: 1.1001x; 1.0127x over previous
//
#include <hip/hip_runtime.h>

// Causal self-attention fwd: x(4,2048,1024)fp32, W_qkv(1024,3072), W_proj(1024,1024)
// Pipeline (5 launches): [k_prep: W transposes + x->bf16 + RoPE table]
//   [GEMM1 qkv + fused V-transpose] [k_ropek: K-RoPE in-place, 32MB]
//   [flash attn w/ fused Q-RoPE] [GEMM2 128x64 tiles]
// R6: swapped QK^T + in-register P via cvt_pk_bf16 + permlane swaps (no P LDS).
// R13: K/V LDS 128B rows + XOR swizzle (0 conflicts).
// R14/R15: latency-bound kernels want TLP (attn 1024 blocks, GEMM2 128x64).
// R16: XCD 2D chunking on both GEMMs (GEMM1 FETCH 71.9->44.9MB, dur restored).
//   GEMM1 now at its structural ceiling (~747 TF, m97-class 2-phase) - frozen.
// R17: attn softmax denominator on the MFMA pipe: dsum = mfma(P_frag, ones)
//   replaces 32 fp32 lsum adds/iter (VALU, on the exp2 dep chain) with 4 MFMA
//   on the ~20%-utilized matrix pipe. Result arrives in C/D layout (lane reg r
//   = row quad*4+r) = exactly the epilogue's row -> both shfl_xor reduces and
//   the per-r shfl deleted; inv = 1/dsum[mi][r]. Denominator now sums the SAME
//   bf16 P as the numerator (consistency up).

#define BATCH 4
#define SEQ   2048
#define DM    1024
#define NH    16
#define HD    64
#define QKV_W 3072

typedef short bf16x8 __attribute__((ext_vector_type(8)));
typedef float f32x4  __attribute__((ext_vector_type(4)));
typedef unsigned u32x4 __attribute__((ext_vector_type(4)));
typedef unsigned short bf16_t;

#define NLT 0.28782313662425575f    // ln(10000)/32

__device__ __forceinline__ unsigned short f2bf(float f) {
  unsigned u = __float_as_uint(f);
  u += 0x7fffu + ((u >> 16) & 1u);   // round-to-nearest-even
  return (unsigned short)(u >> 16);
}
__device__ __forceinline__ float bf2f(unsigned short s) {
  return __uint_as_float((unsigned)s << 16);
}
// async global->LDS, 16B per lane; LDS dest is wave-uniform base + lane*16
__device__ __forceinline__ void gld16(const void* g, void* l) {
  __builtin_amdgcn_global_load_lds(
      (const __attribute__((address_space(1))) unsigned int*)g,
      (__attribute__((address_space(3))) unsigned int*)l, 16, 0, 0);
}
// packed f32x2 -> bf16x2 (RTNE), lo=a hi=b
__device__ __forceinline__ unsigned cvt_pk_bf16(float a, float b) {
  unsigned r;
  asm("v_cvt_pk_bf16_f32 %0, %1, %2" : "=v"(r) : "v"(a), "v"(b));
  return r;
}
// a.rows{2,3} <-> b.rows{0,1}  (rows = 16-lane groups)
__device__ __forceinline__ void permlane32_swap(unsigned& a, unsigned& b) {
  asm("v_permlane32_swap_b32 %0, %1" : "+v"(a), "+v"(b));
}
// a.rows{1,3} <-> b.rows{0,2}
__device__ __forceinline__ void permlane16_swap(unsigned& a, unsigned& b) {
  asm("v_permlane16_swap_b32 %0, %1" : "+v"(a), "+v"(b));
}

// ---- prep: W transposes (fp32->bf16) + x->bf16 + RoPE cos/sin table --------
// blocks [0,3072): Wqkv transpose; [3072,4096): Wproj; [4096,12288): x cvt;
// [12288,12544): tab[s][i] = (cos, sin)(s * 10000^(-i/32)), accurate sincosf.
__global__ __launch_bounds__(256) void k_prep(const float* __restrict__ W1,
                                              const float* __restrict__ W2,
                                              const float* __restrict__ x,
                                              bf16_t* __restrict__ Wt1,
                                              bf16_t* __restrict__ Wt2,
                                              bf16_t* __restrict__ xb,
                                              float2* __restrict__ tab) {
  __shared__ float tile[32][33];
  const int blk = blockIdx.x, tid = threadIdx.x;
  if (blk < 4096) {
    const float* W;
    bf16_t* Wt;
    int N, bx, by;
    if (blk < 3072) { W = W1; Wt = Wt1; N = QKV_W; bx = blk % 96; by = blk / 96; }
    else            { W = W2; Wt = Wt2; N = DM;    bx = (blk - 3072) & 31; by = (blk - 3072) >> 5; }
    const int tx = tid & 31, ty = tid >> 5;   // (32,8)
    const int n0 = bx * 32, k0 = by * 32;
#pragma unroll
    for (int j = 0; j < 4; ++j)
      tile[ty + j * 8][tx] = W[(size_t)(k0 + ty + j * 8) * N + n0 + tx];
    __syncthreads();
#pragma unroll
    for (int j = 0; j < 4; ++j)
      Wt[(size_t)(n0 + ty + j * 8) * DM + k0 + tx] = f2bf(tile[tx][ty + j * 8]);
  } else if (blk < 12288) {
    const int i = ((blk - 4096) * 256 + tid) * 4;
    float4 v = *(const float4*)(x + i);
    unsigned lo = (unsigned)f2bf(v.x) | ((unsigned)f2bf(v.y) << 16);
    unsigned hi = (unsigned)f2bf(v.z) | ((unsigned)f2bf(v.w) << 16);
    *(uint2*)(xb + i) = make_uint2(lo, hi);
  } else {
    const int idx = (blk - 12288) * 256 + tid;   // 0..65535
    const int s = idx >> 5, i = idx & 31;
    const float inv = __expf((float)i * -NLT);
    float sn, cs;
    sincosf((float)s * inv, &sn, &cs);           // accurate
    tab[idx] = make_float2(cs, sn);
  }
}

// ---------------- K-RoPE in place (K section of qkv), table-driven ----------
// 8192 rows x 1024 K-cols bf16 = 16MB; 128 threads/row, bf16x8 (4 pairs) each.
__global__ __launch_bounds__(256) void k_ropek(bf16_t* __restrict__ qkv,
                                               const float2* __restrict__ tab) {
  const int t = blockIdx.x * 256 + threadIdx.x;   // 0..1048575
  const int row = t >> 7;
  const int c = (t & 127) * 8;         // col within K section
  const int i0 = (c & 63) >> 1;        // first pair index in head
  bf16_t* p = qkv + (size_t)row * QKV_W + DM + c;
  bf16x8 v = *(const bf16x8*)p;
  const float2* tq = tab + (size_t)(row & 2047) * 32 + i0;
  bf16x8 r;
#pragma unroll
  for (int k = 0; k < 4; ++k) {
    const float2 cs = tq[k];
    const float e = bf2f((unsigned short)v[2 * k]);
    const float o = bf2f((unsigned short)v[2 * k + 1]);
    r[2 * k]     = (short)f2bf(e * cs.x - o * cs.y);
    r[2 * k + 1] = (short)f2bf(e * cs.y + o * cs.x);
  }
  *(bf16x8*)p = r;
}

// ---------------- 128x128 bf16 GEMM (2-phase) — GEMM1 ----------------
// R16: 1D grid 1536, XCD 2D chunking: xcd = bid&7 owns a 12bx x 16by chunk.
// qkv epilogue: cols<2048 (Q,K) bf16 row-major; cols>=2048 (V) -> vt packed.
__global__ __launch_bounds__(256) void k_gemm(const bf16_t* __restrict__ A,
                                              const bf16_t* __restrict__ Bt,
                                              bf16_t* __restrict__ Cout,
                                              bf16_t* __restrict__ vt,
                                              int M, int N, int K) {
  __shared__ __align__(16) short As[128 * 64];
  __shared__ __align__(16) short Bs[128 * 64];
  const int tid = threadIdx.x;
  const int wave = tid >> 6, lane = tid & 63;
  const int quad = lane >> 4, l16 = lane & 15;
  const int wm = (wave >> 1) * 64, wn = (wave & 1) * 64;
  // XCD chunking: 8 XCDs = 2 x-chunks (12 bx) x 4 y-chunks (16 by)
  const int bid = (int)blockIdx.x;
  const int xcd = bid & 7, w = bid >> 3;          // w in [0,192)
  const int bx = (xcd & 1) * 12 + w % 12;
  const int by = (xcd >> 1) * 16 + w / 12;
  const int bm = by * 128, bn = bx * 128;

  f32x4 acc[4][4];
#pragma unroll
  for (int i = 0; i < 4; ++i)
#pragma unroll
    for (int j = 0; j < 4; ++j) acc[i][j] = f32x4{0.f, 0.f, 0.f, 0.f};

  const int srow = tid >> 3;                       // 0..31
  const int sg   = (tid & 7) ^ (srow & 7);         // swizzled source granule
  const bf16_t* Ap = A  + (size_t)(bm + srow) * K + sg * 8;
  const bf16_t* Bp = Bt + (size_t)(bn + srow) * K + sg * 8;
  short* Ad = As + tid * 8;
  short* Bd = Bs + tid * 8;

  for (int k0 = 0; k0 < K; k0 += 64) {
    __syncthreads();
#pragma unroll
    for (int pp = 0; pp < 4; ++pp) {
      gld16(Ap + (size_t)(pp * 32) * K + k0, Ad + pp * 2048);
      gld16(Bp + (size_t)(pp * 32) * K + k0, Bd + pp * 2048);
    }
    __syncthreads();
#pragma unroll
    for (int ks = 0; ks < 2; ++ks) {
      bf16x8 af[4], bfr[4];
#pragma unroll
      for (int i = 0; i < 4; ++i)
        af[i] = *(const bf16x8*)&As[(wm + i * 16 + l16) * 64 +
                                    (((ks * 4 + quad) ^ (l16 & 7)) << 3)];
#pragma unroll
      for (int j = 0; j < 4; ++j)
        bfr[j] = *(const bf16x8*)&Bs[(wn + j * 16 + l16) * 64 +
                                     (((ks * 4 + quad) ^ (l16 & 7)) << 3)];
#pragma unroll
      for (int i = 0; i < 4; ++i)
#pragma unroll
        for (int j = 0; j < 4; ++j)
          acc[i][j] = __builtin_amdgcn_mfma_f32_16x16x32_bf16(af[i], bfr[j], acc[i][j], 0, 0, 0);
    }
  }
  // C row = quad*4+reg, col = l16 (verified mapping)
#pragma unroll
  for (int i = 0; i < 4; ++i)
#pragma unroll
    for (int j = 0; j < 4; ++j) {
      const int col = bn + wn + j * 16 + l16;
      const int row0 = bm + wm + i * 16 + quad * 4;
      if (col >= 2048) {
        const int d = col - 2048;
        const int hh = d >> 6, dd = d & 63;
        const int bb = row0 >> 11, ss = row0 & 2047;
        ushort4 pk;
        pk.x = f2bf(acc[i][j][0]); pk.y = f2bf(acc[i][j][1]);
        pk.z = f2bf(acc[i][j][2]); pk.w = f2bf(acc[i][j][3]);
        *(ushort4*)(vt + ((size_t)((bb * NH + hh) * HD + dd)) * SEQ + ss) = pk;
      } else {
#pragma unroll
        for (int r = 0; r < 4; ++r)
          Cout[(size_t)(row0 + r) * N + col] = f2bf(acc[i][j][r]);
      }
    }
}

// ---------------- GEMM2: out(fp32) = y * Wt2^T, 128x64 tiles ----------------
// R15: 1024 blocks = 4 blocks/CU. R16: XCD chunking 8bx x 16by per XCD.
__global__ __launch_bounds__(256, 4) void k_gemm2(const bf16_t* __restrict__ A,
                                                  const bf16_t* __restrict__ Bt,
                                                  float* __restrict__ Cout,
                                                  int M, int N, int K) {
  __shared__ __align__(16) short As[128 * 64];
  __shared__ __align__(16) short Bs[64 * 64];
  const int tid = threadIdx.x;
  const int wave = tid >> 6, lane = tid & 63;
  const int quad = lane >> 4, l16 = lane & 15;
  const int wm = (wave >> 1) * 64, wn = (wave & 1) * 32;
  const int bid = (int)blockIdx.x;
  const int xcd = bid & 7, w = bid >> 3;          // w in [0,128)
  const int bx = (xcd & 1) * 8 + (w & 7);
  const int by = (xcd >> 1) * 16 + (w >> 3);
  const int bm = by * 128, bn = bx * 64;

  f32x4 acc[4][2];
#pragma unroll
  for (int i = 0; i < 4; ++i)
#pragma unroll
    for (int j = 0; j < 2; ++j) acc[i][j] = f32x4{0.f, 0.f, 0.f, 0.f};

  const int srow = tid >> 3;                       // 0..31
  const int sg   = (tid & 7) ^ (srow & 7);         // swizzled source granule
  const bf16_t* Ap = A  + (size_t)(bm + srow) * K + sg * 8;
  const bf16_t* Bp = Bt + (size_t)(bn + srow) * K + sg * 8;
  short* Ad = As + tid * 8;
  short* Bd = Bs + tid * 8;

  for (int k0 = 0; k0 < K; k0 += 64) {
    __syncthreads();
#pragma unroll
    for (int pp = 0; pp < 4; ++pp)
      gld16(Ap + (size_t)(pp * 32) * K + k0, Ad + pp * 2048);
#pragma unroll
    for (int pp = 0; pp < 2; ++pp)
      gld16(Bp + (size_t)(pp * 32) * K + k0, Bd + pp * 2048);
    __syncthreads();
#pragma unroll
    for (int ks = 0; ks < 2; ++ks) {
      bf16x8 af[4], bfr[2];
#pragma unroll
      for (int i = 0; i < 4; ++i)
        af[i] = *(const bf16x8*)&As[(wm + i * 16 + l16) * 64 +
                                    (((ks * 4 + quad) ^ (l16 & 7)) << 3)];
#pragma unroll
      for (int j = 0; j < 2; ++j)
        bfr[j] = *(const bf16x8*)&Bs[(wn + j * 16 + l16) * 64 +
                                     (((ks * 4 + quad) ^ (l16 & 7)) << 3)];
#pragma unroll
      for (int i = 0; i < 4; ++i)
#pragma unroll
        for (int j = 0; j < 2; ++j)
          acc[i][j] = __builtin_amdgcn_mfma_f32_16x16x32_bf16(af[i], bfr[j], acc[i][j], 0, 0, 0);
    }
  }
#pragma unroll
  for (int i = 0; i < 4; ++i)
#pragma unroll
    for (int j = 0; j < 2; ++j) {
      const int col = bn + wn + j * 16 + l16;
      const int row0 = bm + wm + i * 16 + quad * 4;
#pragma unroll
      for (int r = 0; r < 4; ++r)
        Cout[(size_t)(row0 + r) * N + col] = acc[i][j][r];
    }
}

// ---------------- flash attention ----------------
// R14: 1024 blocks, ONE 128-row Q-tile each (4 waves x 32q), longest-first
// (qt = 15 - blk/64); 4 blocks/CU. KV dbuf + cross-iter prefetch, 1 barrier/iter.
// Q pre-scaled by 0.125*log2e => p = exp2(s'). Q-RoPE fused via table.
// Swapped QK^T: S^T = mfma(K, Q); lane holds P[q=l16][k=jn*16+quad*4+r];
// PV A-frags in-register via cvt_pk + permlane32/16 swaps — no P LDS.
// K/V tiles [64][64] shorts (128B rows) + slot^(l16&7) XOR swizzle (0-conflict).
// R17: denominator via ones-MFMA (dsum = mfma(ap, ones)); no lsum VALU adds,
// no cross-lane reduce; dsum[mi][r] is row quad*4+r's sum = epilogue's own row.
#define QSCALE 0.18033688011112042f   // 0.125 * log2(e)
__global__ __launch_bounds__(256, 4) void k_attn(const bf16_t* __restrict__ qkv,
                                                 const bf16_t* __restrict__ vt,
                                                 const float2* __restrict__ tab,
                                                 bf16_t* __restrict__ y) {
  __shared__ __align__(16) short Kb[2][64 * 64];   // [buf][kv-row][k-dim]
  __shared__ __align__(16) short Vb[2][64 * 64];   // [buf][d-row][kv-dim]
  const int tid = threadIdx.x;
  const int lane = tid & 63;
  const int quad = lane >> 4, l16 = lane & 15;
  const int wave = tid >> 6;
  const int xs = l16 & 7;
  const int l = blockIdx.x;
  const int qt = 15 - (l >> 6);                  // longest tiles first
  const int hb = l & 63;
  const int h = hb & 15, b = hb >> 4;
  const size_t bbase = (size_t)b * SEQ * QKV_W;
  // staging: thread t -> LDS row (t>>3) and (t>>3)+32, slot t&7;
  // source granule pre-swizzled: sg = (t&7) ^ ((t>>3)&7)  [(r+32)&7 == r&7]
  const int sr8 = tid >> 3;                      // 0..31
  const int sg  = (tid & 7) ^ (sr8 & 7);
  const bf16_t* kbase = qkv + bbase + (size_t)sr8 * QKV_W + DM + h * HD + sg * 8;
  const bf16_t* vbase = vt + ((size_t)(b * NH + h) * HD + sr8) * SEQ + sg * 8;

  // ones B-frag for the denominator MFMA (bf16 1.0 = 0x3F80)
  bf16x8 vones;
#pragma unroll
  for (int e = 0; e < 8; ++e) vones[e] = (short)0x3F80;

#define ISSUE(kv0, buf)                                                   \
  do {                                                                    \
    gld16(kbase + (size_t)(kv0) * QKV_W,        &Kb[buf][tid * 8]);       \
    gld16(kbase + (size_t)((kv0) + 32) * QKV_W, &Kb[buf][2048 + tid * 8]);\
    gld16(vbase + (kv0),                        &Vb[buf][tid * 8]);       \
    gld16(vbase + (size_t)32 * SEQ + (kv0),     &Vb[buf][2048 + tid * 8]);\
  } while (0)

  int bufp = 0;
  ISSUE(0, 0);
  const int qb = qt * 128 + wave * 32;           // wave's first q row
  // load Q fragments; apply RoPE (in-lane pairs, table) + QSCALE in fp32
  bf16x8 aq[2][2];
#pragma unroll
  for (int mi = 0; mi < 2; ++mi) {
    const float2* tq = tab + (size_t)(qb + mi * 16 + l16) * 32;
#pragma unroll
    for (int kk = 0; kk < 2; ++kk) {
      const bf16_t* qp = qkv + bbase + (size_t)(qb + mi * 16 + l16) * QKV_W +
                         h * HD + kk * 32 + quad * 8;
      bf16x8 raw = *(const bf16x8*)qp;
      bf16x8 sc;
#pragma unroll
      for (int t = 0; t < 4; ++t) {
        const float2 cs = tq[kk * 16 + quad * 4 + t];
        const float e = bf2f((unsigned short)raw[2 * t]);
        const float o = bf2f((unsigned short)raw[2 * t + 1]);
        sc[2 * t]     = (short)f2bf((e * cs.x - o * cs.y) * QSCALE);
        sc[2 * t + 1] = (short)f2bf((e * cs.y + o * cs.x) * QSCALE);
      }
      aq[mi][kk] = sc;
    }
  }
  f32x4 o[2][4];
  f32x4 dsum[2];
#pragma unroll
  for (int mi = 0; mi < 2; ++mi) {
    dsum[mi] = f32x4{0.f, 0.f, 0.f, 0.f};
#pragma unroll
    for (int jn = 0; jn < 4; ++jn) o[mi][jn] = f32x4{0.f, 0.f, 0.f, 0.f};
  }
  const int qr0 = qb + l16;                      // this lane's q row (mi=0)

  const int jmax = 2 * qt + 1;
  for (int j = 0; j <= jmax; ++j) {
    const int kv0 = j * 64;
    __syncthreads();   // drains this buf's loads; WAR-protects prefetch target
    if (j < jmax) ISSUE(kv0 + 64, bufp ^ 1);
    if (kv0 <= qb + 31) {  // else: fully masked for this wave — skip
      const bool needmask = (kv0 + 63 > qb);
      const short* Kc = &Kb[bufp][0];
      const short* Vc = &Vb[bufp][0];

      // S^T frags: st[jn][mi]; row = kv (jn*16+quad*4+r), col = q (mi*16+l16)
      f32x4 st[4][2];
#pragma unroll
      for (int jn = 0; jn < 4; ++jn) {
        const int krow = (jn * 16 + l16) * 64;
        bf16x8 ak0 = *(const bf16x8*)&Kc[krow + ((quad ^ xs) << 3)];
        bf16x8 ak1 = *(const bf16x8*)&Kc[krow + (((4 + quad) ^ xs) << 3)];
#pragma unroll
        for (int mi = 0; mi < 2; ++mi) {
          f32x4 s4 = f32x4{0.f, 0.f, 0.f, 0.f};
          s4 = __builtin_amdgcn_mfma_f32_16x16x32_bf16(ak0, aq[mi][0], s4, 0, 0, 0);
          s4 = __builtin_amdgcn_mfma_f32_16x16x32_bf16(ak1, aq[mi][1], s4, 0, 0, 0);
          st[jn][mi] = s4;
        }
      }
      // p = exp2(s'); mask near diagonal; pack r-pairs to bf16x2
      unsigned pk[4][2][2];
#pragma unroll
      for (int jn = 0; jn < 4; ++jn)
#pragma unroll
        for (int mi = 0; mi < 2; ++mi) {
          const int kvb = kv0 + jn * 16 + quad * 4;
          const int qr = qr0 + mi * 16;
          float e[4];
#pragma unroll
          for (int r = 0; r < 4; ++r) {
            float v = __builtin_amdgcn_exp2f(st[jn][mi][r]);
            if (needmask) v = (kvb + r <= qr) ? v : 0.f;
            e[r] = v;
          }
          pk[jn][mi][0] = cvt_pk_bf16(e[0], e[1]);
          pk[jn][mi][1] = cvt_pk_bf16(e[2], e[3]);
        }
      // redistribute across quads -> PV A-frags ap[mi][ks]
      bf16x8 ap[2][2];
#pragma unroll
      for (int mi = 0; mi < 2; ++mi)
#pragma unroll
        for (int ks = 0; ks < 2; ++ks) {
          unsigned a0 = pk[2 * ks][mi][0], b0 = pk[2 * ks + 1][mi][0];
          permlane32_swap(a0, b0);
          permlane16_swap(a0, b0);
          unsigned a1 = pk[2 * ks][mi][1], b1 = pk[2 * ks + 1][mi][1];
          permlane32_swap(a1, b1);
          permlane16_swap(a1, b1);
          union { u32x4 u; bf16x8 s; } f;
          f.u = (u32x4){a0, a1, b0, b1};
          ap[mi][ks] = f.s;
        }
      // O += P V; denominator on the MFMA pipe: dsum += P . ones
#pragma unroll
      for (int ks = 0; ks < 2; ++ks) {
        dsum[0] = __builtin_amdgcn_mfma_f32_16x16x32_bf16(ap[0][ks], vones, dsum[0], 0, 0, 0);
        dsum[1] = __builtin_amdgcn_mfma_f32_16x16x32_bf16(ap[1][ks], vones, dsum[1], 0, 0, 0);
#pragma unroll
        for (int jn = 0; jn < 4; ++jn) {
          bf16x8 bv = *(const bf16x8*)&Vc[(jn * 16 + l16) * 64 +
                                          (((ks * 4 + quad) ^ xs) << 3)];
          o[0][jn] = __builtin_amdgcn_mfma_f32_16x16x32_bf16(ap[0][ks], bv, o[0][jn], 0, 0, 0);
          o[1][jn] = __builtin_amdgcn_mfma_f32_16x16x32_bf16(ap[1][ks], bv, o[1][jn], 0, 0, 0);
        }
      }
    }
    bufp ^= 1;
  }
  // normalize + write: dsum[mi][r] is the row-sum for q row quad*4+r (+mi*16)
  // — the exact row this lane writes; no cross-lane reduce needed.
#pragma unroll
  for (int mi = 0; mi < 2; ++mi)
#pragma unroll
    for (int r = 0; r < 4; ++r) {
      const float invr = 1.0f / dsum[mi][r];
      const int qr = qb + mi * 16 + quad * 4 + r;
      bf16_t* yp = y + ((size_t)b * SEQ + qr) * DM + h * HD;
#pragma unroll
      for (int jn = 0; jn < 4; ++jn)
        yp[jn * 16 + l16] = f2bf(o[mi][jn][r] * invr);
    }
#undef ISSUE
}

extern "C" void kernel_launch(void* const* d_in, const int* in_sizes, int n_in,
                              void* d_out, int out_size, void* d_ws, size_t ws_size,
                              hipStream_t stream) {
  const float* x     = (const float*)d_in[0];
  const float* Wqkv  = (const float*)d_in[1];
  const float* Wproj = (const float*)d_in[2];
  float* out = (float*)d_out;
  char* ws = (char*)d_ws;
  // ws layout (72 MiB):
  bf16_t* qkv = (bf16_t*)(ws);                 // 48 MiB (V third unused)
  bf16_t* Wt1 = (bf16_t*)(ws + 50331648);      // 6 MiB
  bf16_t* Wt2 = (bf16_t*)(ws + 56623104);      // 2 MiB
  bf16_t* xb  = (bf16_t*)(ws + 58720256);      // 16 MiB (dead after GEMM1)
  bf16_t* y   = xb;                            // attn output aliases xb
  // d_out scratch: V^T in first 16 MiB, RoPE table in next 512 KiB; both dead
  // before GEMM2 overwrites d_out.
  bf16_t* vt  = (bf16_t*)d_out;
  float2* tab = (float2*)((char*)d_out + 16777216);

  k_prep<<<12544, 256, 0, stream>>>(Wqkv, Wproj, x, Wt1, Wt2, xb, tab);
  k_gemm<<<1536, 256, 0, stream>>>(xb, Wt1, qkv, vt, BATCH * SEQ, QKV_W, DM);
  k_ropek<<<4096, 256, 0, stream>>>(qkv, tab);
  k_attn<<<1024, 256, 0, stream>>>(qkv, vt, tab, y);
  k_gemm2<<<1024, 256, 0, stream>>>(y, Wt2, out, BATCH * SEQ, DM, DM);
}